// Round 6
// baseline (855.299 us; speedup 1.0000x reference)
//
#include <hip/hip_runtime.h>
#include <math.h>

#define DEV __device__ __forceinline__

typedef __attribute__((ext_vector_type(8))) short bf16x8;
typedef __attribute__((ext_vector_type(4))) float f32x4;

DEV short f2bf(float v) {
    union { float f; unsigned u; } c; c.f = v;
    unsigned r = c.u + 0x7fffu + ((c.u >> 16) & 1u);   // RNE
    return (short)(r >> 16);
}
DEV float bf2f(short s) {
    return __uint_as_float(((unsigned)(unsigned short)s) << 16);
}

// ===========================================================================
// Weight packing: W [KIN][NOUT] f32 (optionally minus Wsub) -> bf16 MFMA-B
// fragments. layout: out[ks*(NOUT*32) + n*32 + kg*8 + i] = W[ks*32+kg*8+i][n]
// ===========================================================================
#define NPACK 20
struct PackJobs {
    const float* W[NPACK];
    const float* Wsub[NPACK];
    int KIN[NPACK];
    int NOUT[NPACK];
    int end[NPACK];
};

__global__ __launch_bounds__(256)
void pack_all(PackJobs j, short* __restrict__ out, int total)
{
    const int idx = blockIdx.x * 256 + threadIdx.x;
    if (idx >= total) return;
    int job = 0;
    while (idx >= j.end[job]) ++job;
    const int base = job ? j.end[job - 1] : 0;
    const int w = idx - base;
    const int nout = j.NOUT[job];
    const int per_ks = nout * 32;
    const int ks = w / per_ks;
    const int r  = w - ks * per_ks;
    const int n  = r >> 5;
    const int kg = (r >> 3) & 3;
    const int i  = r & 7;
    const int k  = ks * 32 + kg * 8 + i;
    float val = 0.0f;
    if (k < j.KIN[job]) {
        val = j.W[job][(size_t)k * nout + n];
        if (j.Wsub[job]) val -= j.Wsub[job][(size_t)k * nout + n];
    }
    out[idx] = f2bf(val);
}

// ===========================================================================
// Sorting by dst: histogram -> single-block scan -> scatter
// ===========================================================================
__global__ __launch_bounds__(256)
void hist_kernel(const int* __restrict__ dst, int* __restrict__ cnt, int E)
{
    const int e = blockIdx.x * 256 + threadIdx.x;
    if (e < E) atomicAdd(&cnt[dst[e]], 1);
}

__global__ __launch_bounds__(1024)
void scan_kernel(int* __restrict__ cnt, int NB)
{
    __shared__ int part[1024];
    const int t = threadIdx.x;
    const int CH = (NB + 1023) >> 10;
    const int base = t * CH;
    int s = 0;
    for (int k = 0; k < CH; ++k) { const int i = base + k; if (i < NB) s += cnt[i]; }
    part[t] = s;
    __syncthreads();
    for (int off = 1; off < 1024; off <<= 1) {
        const int add = (t >= off) ? part[t - off] : 0;
        __syncthreads();
        part[t] += add;
        __syncthreads();
    }
    int run = part[t] - s;
    for (int k = 0; k < CH; ++k) {
        const int i = base + k;
        if (i < NB) { const int c = cnt[i]; cnt[i] = run; run += c; }
    }
}

__global__ __launch_bounds__(256)
void scatter_kernel(const int* __restrict__ src, const int* __restrict__ dst,
                    const float* __restrict__ ea, int* __restrict__ cursor,
                    int* __restrict__ sSrc, int* __restrict__ sDst,
                    short* __restrict__ eaB, int E)
{
    const int e = blockIdx.x * 256 + threadIdx.x;
    if (e >= E) return;
    const int d = dst[e];
    const int p = atomicAdd(&cursor[d], 1);
    sSrc[p] = src[e];
    sDst[p] = d;
    const float4 a = ((const float4*)ea)[e];
    *(short4*)(eaB + (size_t)p * 4) =
        make_short4(f2bf(a.x), f2bf(a.y), f2bf(a.z), f2bf(a.w));
}

// ===========================================================================
// MFMA GEMM over an LDS row-tile (used by uv_pre / node / fusion)
// ===========================================================================
template<int KP, int FSTR, int NOUT, bool BIAS>
DEV void mfma_gemm(const short* aLds, const short* __restrict__ Wpk,
                   const float* __restrict__ b, int row0, int c0, int lane,
                   f32x4 (&acc)[8])
{
    const int l15 = lane & 15;
    const int lg  = lane >> 4;
#pragma unroll
    for (int f = 0; f < 8; ++f) {
        if (BIAS) {
            const float bv = b[c0 + f * 16 + l15];
            acc[f] = (f32x4){bv, bv, bv, bv};
        } else {
            acc[f] = (f32x4){0.f, 0.f, 0.f, 0.f};
        }
    }
    const short* arow  = aLds + (row0 + l15) * FSTR + lg * 8;
    const short* wbase = Wpk + (size_t)(c0 + l15) * 32 + lg * 8;
#pragma unroll
    for (int ks = 0; ks < KP / 32; ++ks) {
        const bf16x8 av = *(const bf16x8*)(arow + ks * 32);
        const short* wp = wbase + (size_t)ks * NOUT * 32;
#pragma unroll
        for (int f = 0; f < 8; ++f) {
            const bf16x8 bv = *(const bf16x8*)(wp + f * 512);
            acc[f] = __builtin_amdgcn_mfma_f32_16x16x32_bf16(av, bv, acc[f], 0, 0, 0);
        }
    }
}

// relu(acc [+ lds]) -> packed bf16 rows in LDS
template<int OSTR, bool ADDLDS>
DEV void pack_relu(const f32x4 (&acc)[8], short* out, int row0, int c0, int lane)
{
    const int l15 = lane & 15;
    const int lg  = lane >> 4;
#pragma unroll
    for (int f = 0; f < 8; ++f)
#pragma unroll
        for (int i = 0; i < 4; ++i) {
            const int row = row0 + lg * 4 + i;
            const int col = c0 + f * 16 + l15;
            float vv = acc[f][i];
            if (ADDLDS) vv += bf2f(out[row * OSTR + col]);
            vv = fmaxf(vv, 0.0f);
            const float o = __shfl_xor(vv, 1);
            if (!(lane & 1)) {
                const unsigned pk = ((unsigned)(unsigned short)f2bf(o) << 16) |
                                    (unsigned)(unsigned short)f2bf(vv);
                *(unsigned*)&out[row * OSTR + col] = pk;
            }
        }
}

// acc -> bf16 global rows (paired 4-byte stores)
DEV void store_bf16(const f32x4 (&acc)[8], short* __restrict__ out,
                    int n0, int wave, int lane, int N)
{
    const int l15 = lane & 15;
    const int lg  = lane >> 4;
#pragma unroll
    for (int f = 0; f < 8; ++f)
#pragma unroll
        for (int i = 0; i < 4; ++i) {
            const float vv = acc[f][i];
            const float o = __shfl_xor(vv, 1);
            if (!(lane & 1)) {
                const unsigned pk = ((unsigned)(unsigned short)f2bf(o) << 16) |
                                    (unsigned)(unsigned short)f2bf(vv);
                const int n = n0 + wave * 16 + lg * 4 + i;
                if (n < N)
                    *(unsigned*)&out[(size_t)n * 128 + f * 16 + l15] = pk;
            }
        }
}

// ===========================================================================
// Per-node precompute: u = x@(W1a-W1b)+b1 (bf16), v = x@W1b (bf16),
// sq = ||x||^2, xB = bf16 copy of x.  Barrier-free (wave-local rows).
// ===========================================================================
template<int FIN, int FSTR>
__global__ __launch_bounds__(256)
void uv_pre(const float* __restrict__ xin,
            const short* __restrict__ Wd, const float* __restrict__ b1,
            const short* __restrict__ Wb,
            short* __restrict__ uB, short* __restrict__ vB,
            float* __restrict__ sq, short* __restrict__ xB, int N)
{
    __shared__ __align__(16) short feat[64 * FSTR];
    const int tid = threadIdx.x, lane = tid & 63, wave = tid >> 6;
    const int n0 = blockIdx.x * 64;
    {
        const int r = tid >> 2, s = tid & 3, n = n0 + r;
        short* frow = feat + r * FSTR;
        if (n < N) {
            const float4* xr = (const float4*)(xin + (size_t)n * FIN);
            float ss = 0.f;
#pragma unroll
            for (int d4 = s; d4 < FIN / 4; d4 += 4) {
                const float4 a = xr[d4];
                ss += a.x * a.x + a.y * a.y + a.z * a.z + a.w * a.w;
                const short4 sv = make_short4(f2bf(a.x), f2bf(a.y), f2bf(a.z), f2bf(a.w));
                *(short4*)(frow + d4 * 4) = sv;
                *(short4*)(xB + (size_t)n * FIN + d4 * 4) = sv;
            }
            ss += __shfl_xor(ss, 1); ss += __shfl_xor(ss, 2);
            if (s == 0) sq[n] = ss;
        } else {
            for (int d = s * 4; d < FIN; d += 16) *(short4*)(frow + d) = make_short4(0, 0, 0, 0);
        }
    }
    asm volatile("s_waitcnt lgkmcnt(0)" ::: "memory");
    f32x4 acc[8];
    mfma_gemm<FIN, FSTR, 128, true>(feat, Wd, b1, wave * 16, 0, lane, acc);
    store_bf16(acc, uB, n0, wave, lane, N);
    mfma_gemm<FIN, FSTR, 128, false>(feat, Wb, nullptr, wave * 16, 0, lane, acc);
    store_bf16(acc, vB, n0, wave, lane, N);
}

// ===========================================================================
// Run-max epilogue: per-wave 16-row sub-block, sorted dst.
// ===========================================================================
DEV void emit_runs(const f32x4 (&acc)[8], const int dR,
                   float* __restrict__ agg, const int lg, const int l15)
{
    const int dFirst = __shfl(dR, 0);
    const int dLast  = __shfl(dR, 15);
    if (dFirst == dLast) {                       // sorted => single run
        if (dFirst < 0) return;
#pragma unroll
        for (int f = 0; f < 8; ++f) {
            float m = fmaxf(fmaxf(acc[f][0], acc[f][1]), fmaxf(acc[f][2], acc[f][3]));
            m = fmaxf(m, __shfl_xor(m, 16));
            m = fmaxf(m, __shfl_xor(m, 32));
            if (lg == 0 && m > 0.f)
                atomicMax((int*)agg + (size_t)dFirst * 128 + f * 16 + l15,
                          __float_as_int(m));
        }
    } else {
        const int d0 = __shfl(dR, lg * 4 + 0);
        const int d1 = __shfl(dR, lg * 4 + 1);
        const int d2 = __shfl(dR, lg * 4 + 2);
        const int d3 = __shfl(dR, lg * 4 + 3);
        int cur = d0;
        float mx[8];
#pragma unroll
        for (int f = 0; f < 8; ++f) mx[f] = acc[f][0];
        auto flush = [&](int d) {
            if (d < 0) return;
#pragma unroll
            for (int f = 0; f < 8; ++f)
                if (mx[f] > 0.f)
                    atomicMax((int*)agg + (size_t)d * 128 + f * 16 + l15,
                              __float_as_int(mx[f]));
        };
#pragma unroll
        for (int i = 1; i < 4; ++i) {
            const int di = (i == 1) ? d1 : (i == 2) ? d2 : d3;
            const bool same = (di == cur);
            if (!same) { flush(cur); cur = di; }
#pragma unroll
            for (int f = 0; f < 8; ++f)
                mx[f] = same ? fmaxf(mx[f], acc[f][i]) : acc[f][i];
        }
        flush(cur);
    }
}

// ===========================================================================
// Edge conv v4: barrier-free; 4 waves x 32 edges per 256-thread block.
// A-fragments of GEMM1 gathered directly from bf16 xB (no feat LDS);
// h1 = relu(p@Wp + [e1,e2,ea]@Wtail + u[dst] + v[src]); m = relu(h1@W2+b2);
// in-register run-max -> atomicMax.
// ===========================================================================
template<int FIN>
__global__ __launch_bounds__(256, 3)
void edge_conv4(const short* __restrict__ xB,
                const int* __restrict__ sSrc, const int* __restrict__ sDst,
                const short* __restrict__ eaB, const float* __restrict__ sq,
                const short* __restrict__ uB, const short* __restrict__ vB,
                const short* __restrict__ W1pk, const short* __restrict__ W2pk,
                const float* __restrict__ b2,
                float* __restrict__ agg, int E, int swzQ, int swzR)
{
    constexpr int KSX = FIN / 32;      // x-part k-steps
    constexpr int KS1 = KSX + 1;       // + tail (e1,e2,ea)
    constexpr int H1STR = 136;
    __shared__ __align__(16) short h1s[128 * H1STR];
    const int tid = threadIdx.x, lane = tid & 63, wave = tid >> 6;
    const int l15 = lane & 15, lg = lane >> 4;
    int bid = blockIdx.x;
    {   // bijective XCD-chunk swizzle
        const int xcd = bid & 7, idx = bid >> 3;
        bid = (xcd < swzR ? xcd * (swzQ + 1)
                          : swzR * (swzQ + 1) + (xcd - swzR) * swzQ) + idx;
    }
    const int e0 = bid * 128 + wave * 32;
    const int wrow0 = wave * 32;

    // ---- row indices (lane l15 owns row sb*16+l15) ----
    int srcR[2], dstR[2];
#pragma unroll
    for (int sb = 0; sb < 2; ++sb) {
        const int e = e0 + sb * 16 + l15;
        const bool ok = (e < E);
        const int ec = ok ? e : E - 1;
        srcR[sb] = sSrc[ec];
        dstR[sb] = ok ? sDst[ec] : -1;
    }

    // ---- gather x fragments, build p in-register ----
    bf16x8 pf[2][KS1];
#pragma unroll
    for (int sb = 0; sb < 2; ++sb) {
        const int dsafe = (dstR[sb] < 0) ? srcR[sb] : dstR[sb];
        const short* xsrow = xB + (size_t)srcR[sb] * FIN + lg * 8;
        const short* xdrow = xB + (size_t)dsafe * FIN + lg * 8;
        float sp = 0.f;
#pragma unroll
        for (int ks = 0; ks < KSX; ++ks) {
            const bf16x8 a = *(const bf16x8*)(xsrow + ks * 32);
            const bf16x8 b = *(const bf16x8*)(xdrow + ks * 32);
            bf16x8 p;
#pragma unroll
            for (int jj = 0; jj < 8; ++jj) {
                const float pj = bf2f(a[jj]) * bf2f(b[jj]);
                sp += pj;
                p[jj] = f2bf(pj);
            }
            pf[sb][ks] = p;
        }
        sp += __shfl_xor(sp, 16);
        sp += __shfl_xor(sp, 32);
        bf16x8 t = (bf16x8){0, 0, 0, 0, 0, 0, 0, 0};
        if (lg == 0) {
            const int e = e0 + sb * 16 + l15;
            const int ec = (e < E) ? e : E - 1;
            const float e1v = sqrtf(fmaxf(sq[srcR[sb]] + sq[dsafe] - 2.f * sp, 0.f));
            const short4 ea = *(const short4*)(eaB + (size_t)ec * 4);
            t[0] = f2bf(e1v); t[1] = f2bf(sp);
            t[2] = ea.x; t[3] = ea.y; t[4] = ea.z; t[5] = ea.w;
        }
        pf[sb][KSX] = t;
    }

    // ---- stage uv = u[dst]+v[src] into h1s (2 lanes per edge) ----
    {
        const int r = lane >> 1;          // 0..31 edge within wave
        const int h = lane & 1;           // 64-col half
        const int e = e0 + r;
        const bool ok = (e < E);
        const int ec = ok ? e : E - 1;
        const int si = sSrc[ec], di = sDst[ec];
        const bf16x8* up = (const bf16x8*)(uB + (size_t)di * 128 + h * 64);
        const bf16x8* vp = (const bf16x8*)(vB + (size_t)si * 128 + h * 64);
        short* orow = h1s + (wrow0 + r) * H1STR + h * 64;
#pragma unroll
        for (int t = 0; t < 8; ++t) {
            const bf16x8 uu = up[t], vv = vp[t];
            bf16x8 o;
#pragma unroll
            for (int jj = 0; jj < 8; ++jj)
                o[jj] = ok ? f2bf(bf2f(uu[jj]) + bf2f(vv[jj])) : (short)0;
            *(bf16x8*)(orow + t * 8) = o;
        }
    }

    // ---- GEMM1: both sub-blocks share each B-fragment ----
    f32x4 acc0[8], acc1[8];
#pragma unroll
    for (int f = 0; f < 8; ++f) {
        acc0[f] = (f32x4){0.f, 0.f, 0.f, 0.f};
        acc1[f] = (f32x4){0.f, 0.f, 0.f, 0.f};
    }
    const short* wb1 = W1pk + l15 * 32 + lg * 8;
#pragma unroll
    for (int ks = 0; ks < KS1; ++ks) {
        const short* wp = wb1 + (size_t)ks * 4096;
#pragma unroll
        for (int f = 0; f < 8; ++f) {
            const bf16x8 bv = *(const bf16x8*)(wp + f * 512);
            acc0[f] = __builtin_amdgcn_mfma_f32_16x16x32_bf16(pf[0][ks], bv, acc0[f], 0, 0, 0);
            acc1[f] = __builtin_amdgcn_mfma_f32_16x16x32_bf16(pf[1][ks], bv, acc1[f], 0, 0, 0);
        }
    }

    // uv ds_writes complete (in-wave) before ADDLDS reads
    asm volatile("s_waitcnt lgkmcnt(0)" ::: "memory");
    pack_relu<H1STR, true>(acc0, h1s, wrow0, 0, lane);
    pack_relu<H1STR, true>(acc1, h1s, wrow0 + 16, 0, lane);
    asm volatile("s_waitcnt lgkmcnt(0)" ::: "memory");

    // ---- GEMM2 ----
#pragma unroll
    for (int f = 0; f < 8; ++f) {
        const float bv = b2[f * 16 + l15];
        acc0[f] = (f32x4){bv, bv, bv, bv};
        acc1[f] = (f32x4){bv, bv, bv, bv};
    }
    const short* wb2 = W2pk + l15 * 32 + lg * 8;
    const short* a0 = h1s + (wrow0 + l15) * H1STR + lg * 8;
    const short* a1 = h1s + (wrow0 + 16 + l15) * H1STR + lg * 8;
#pragma unroll
    for (int ks = 0; ks < 4; ++ks) {
        const bf16x8 av0 = *(const bf16x8*)(a0 + ks * 32);
        const bf16x8 av1 = *(const bf16x8*)(a1 + ks * 32);
        const short* wp = wb2 + (size_t)ks * 4096;
#pragma unroll
        for (int f = 0; f < 8; ++f) {
            const bf16x8 bv = *(const bf16x8*)(wp + f * 512);
            acc0[f] = __builtin_amdgcn_mfma_f32_16x16x32_bf16(av0, bv, acc0[f], 0, 0, 0);
            acc1[f] = __builtin_amdgcn_mfma_f32_16x16x32_bf16(av1, bv, acc1[f], 0, 0, 0);
        }
    }

    // ---- in-register run-max -> atomics ----
    emit_runs(acc0, dstR[0], agg, lg, l15);
    emit_runs(acc1, dstR[1], agg, lg, l15);
}

// ===========================================================================
// Node MLP (MFMA, barrier-free): y = relu(relu([x,agg]@W1+b1)@W2+b2) (+x).
// ===========================================================================
template<int FIN, int KP, int FSTR, bool RES>
__global__ __launch_bounds__(256)
void node_mfma(const float* __restrict__ xin, const float* __restrict__ agg,
               const short* __restrict__ W1pk, const float* __restrict__ b1,
               const short* __restrict__ W2pk, const float* __restrict__ b2,
               float* __restrict__ out, int N)
{
    constexpr int H1STR = 136;
    __shared__ __align__(16) short sh[64 * FSTR + 64 * H1STR];
    short* feat = sh;
    short* h1s  = sh + 64 * FSTR;
    const int tid = threadIdx.x, lane = tid & 63, wave = tid >> 6;
    const int n0 = blockIdx.x * 64;

    {
        const int r = tid >> 2, s = tid & 3, n = n0 + r;
        short* frow = feat + r * FSTR;
        if (n < N) {
            const float4* xr = (const float4*)(xin + (size_t)n * FIN);
            const float4* ar = (const float4*)(agg + (size_t)n * 128);
#pragma unroll
            for (int d4 = s; d4 < FIN / 4; d4 += 4) {
                const float4 v = xr[d4];
                *(short4*)(frow + d4 * 4) = make_short4(f2bf(v.x), f2bf(v.y), f2bf(v.z), f2bf(v.w));
            }
#pragma unroll
            for (int d4 = s; d4 < 32; d4 += 4) {
                const float4 v = ar[d4];
                *(short4*)(frow + FIN + d4 * 4) = make_short4(f2bf(v.x), f2bf(v.y), f2bf(v.z), f2bf(v.w));
            }
        } else {
            for (int d = s * 4; d < KP; d += 16) *(short4*)(frow + d) = make_short4(0, 0, 0, 0);
        }
    }
    asm volatile("s_waitcnt lgkmcnt(0)" ::: "memory");

    f32x4 acc[8];
    mfma_gemm<KP, FSTR, 128, true>(feat, W1pk, b1, wave * 16, 0, lane, acc);
    pack_relu<H1STR, false>(acc, h1s, wave * 16, 0, lane);
    asm volatile("s_waitcnt lgkmcnt(0)" ::: "memory");
    mfma_gemm<128, H1STR, 128, true>(h1s, W2pk, b2, wave * 16, 0, lane, acc);
    {
        const int l15 = lane & 15, lg = lane >> 4;
#pragma unroll
        for (int f = 0; f < 8; ++f)
#pragma unroll
            for (int i = 0; i < 4; ++i) {
                const int n = n0 + wave * 16 + lg * 4 + i;
                if (n < N) {
                    const int c = f * 16 + l15;
                    float v = fmaxf(acc[f][i], 0.0f);
                    if (RES) v += xin[(size_t)n * 128 + c];
                    out[(size_t)n * 128 + c] = v;
                }
            }
    }
}

// ===========================================================================
// Fusion MLP (MFMA, barrier-free): out = relu(relu([x1,x2,x3]@W1+b1)@W2+b2).
// ===========================================================================
__global__ __launch_bounds__(128)
void fusion_mfma(const float* __restrict__ x1, const float* __restrict__ x2,
                 const float* __restrict__ x3,
                 const short* __restrict__ W1pk, const float* __restrict__ b1,
                 const short* __restrict__ W2pk, const float* __restrict__ b2,
                 float* __restrict__ out, int N)
{
    constexpr int FSTR = 392;
    constexpr int H1STR = 264;
    __shared__ __align__(16) short sh[32 * FSTR + 32 * H1STR];
    short* feat = sh;
    short* h1s  = sh + 32 * FSTR;
    const int tid = threadIdx.x, lane = tid & 63, wave = tid >> 6;
    const int n0 = blockIdx.x * 32;

    {
        const int r = tid >> 2, s = tid & 3, n = n0 + r;
        short* frow = feat + r * FSTR;
        if (n < N) {
            const float4* a1 = (const float4*)(x1 + (size_t)n * 128);
            const float4* a2 = (const float4*)(x2 + (size_t)n * 128);
            const float4* a3 = (const float4*)(x3 + (size_t)n * 128);
#pragma unroll
            for (int d4 = s; d4 < 32; d4 += 4) {
                const float4 v1 = a1[d4], v2 = a2[d4], v3 = a3[d4];
                *(short4*)(frow + d4 * 4)       = make_short4(f2bf(v1.x), f2bf(v1.y), f2bf(v1.z), f2bf(v1.w));
                *(short4*)(frow + 128 + d4 * 4) = make_short4(f2bf(v2.x), f2bf(v2.y), f2bf(v2.z), f2bf(v2.w));
                *(short4*)(frow + 256 + d4 * 4) = make_short4(f2bf(v3.x), f2bf(v3.y), f2bf(v3.z), f2bf(v3.w));
            }
        } else {
            for (int d = s * 4; d < 384; d += 16) *(short4*)(frow + d) = make_short4(0, 0, 0, 0);
        }
    }
    asm volatile("s_waitcnt lgkmcnt(0)" ::: "memory");

    f32x4 acc[8];
#pragma unroll
    for (int c0 = 0; c0 < 256; c0 += 128) {
        mfma_gemm<384, FSTR, 256, true>(feat, W1pk, b1, wave * 16, c0, lane, acc);
        pack_relu<H1STR, false>(acc, h1s, wave * 16, c0, lane);
    }
    asm volatile("s_waitcnt lgkmcnt(0)" ::: "memory");
    mfma_gemm<256, H1STR, 128, true>(h1s, W2pk, b2, wave * 16, 0, lane, acc);
    {
        const int l15 = lane & 15, lg = lane >> 4;
#pragma unroll
        for (int f = 0; f < 8; ++f)
#pragma unroll
            for (int i = 0; i < 4; ++i) {
                const int n = n0 + wave * 16 + lg * 4 + i;
                if (n < N)
                    out[(size_t)n * 128 + f * 16 + l15] = fmaxf(acc[f][i], 0.0f);
            }
    }
}

// ===========================================================================
extern "C" void kernel_launch(void* const* d_in, const int* in_sizes, int n_in,
                              void* d_out, int out_size, void* d_ws, size_t ws_size,
                              hipStream_t stream)
{
    const float* x    = (const float*)d_in[0];
    const int*   eidx = (const int*)d_in[1];
    const float* ea   = (const float*)d_in[2];

    const float* c1_eW1 = (const float*)d_in[3];
    const float* c1_eb1 = (const float*)d_in[4];
    const float* c1_eW2 = (const float*)d_in[5];
    const float* c1_eb2 = (const float*)d_in[6];
    const float* c1_lW1 = (const float*)d_in[7];
    const float* c1_lb1 = (const float*)d_in[8];
    const float* c1_lW2 = (const float*)d_in[9];
    const float* c1_lb2 = (const float*)d_in[10];

    const float* c2_eW1 = (const float*)d_in[11];
    const float* c2_eb1 = (const float*)d_in[12];
    const float* c2_eW2 = (const float*)d_in[13];
    const float* c2_eb2 = (const float*)d_in[14];
    const float* c2_lW1 = (const float*)d_in[15];
    const float* c2_lb1 = (const float*)d_in[16];
    const float* c2_lW2 = (const float*)d_in[17];
    const float* c2_lb2 = (const float*)d_in[18];

    const float* c3_eW1 = (const float*)d_in[19];
    const float* c3_eb1 = (const float*)d_in[20];
    const float* c3_eW2 = (const float*)d_in[21];
    const float* c3_eb2 = (const float*)d_in[22];
    const float* c3_lW1 = (const float*)d_in[23];
    const float* c3_lb1 = (const float*)d_in[24];
    const float* c3_lW2 = (const float*)d_in[25];
    const float* c3_lb2 = (const float*)d_in[26];

    const float* fus_W1 = (const float*)d_in[27];
    const float* fus_b1 = (const float*)d_in[28];
    const float* fus_W2 = (const float*)d_in[29];
    const float* fus_b2 = (const float*)d_in[30];

    const int N = in_sizes[0] / 32;   // 25000
    const int E = in_sizes[1] / 2;    // 400000
    const int* srcI = eidx;
    const int* dstI = eidx + E;

    const size_t NP = (size_t)N * 128;
    float* ws  = (float*)d_ws;
    float* x1  = ws;
    float* x2  = x1 + NP;
    float* x3  = x2 + NP;
    float* agg = x3 + NP;
    float* sq  = agg + NP;
    int* cursor = (int*)(sq + N);
    int* sSrc   = cursor + 25024;
    int* sDst   = sSrc + E;
    short* eaB  = (short*)(sDst + E);
    short* uB   = eaB + (size_t)E * 4;
    short* vB   = uB + NP;
    short* xB   = vB + NP;
    short* wpk  = xB + NP;

    // packed-weight offsets (shorts) — same jobs as R5
    short* e1Wd = wpk + 0;        // KIN 32  KP 32
    short* e1Wb = wpk + 4096;     // KIN 32  KP 32
    short* e1Wp = wpk + 8192;     // KIN 38  KP 64  (p + e1,e2,ea)
    short* e1W2 = wpk + 16384;    // KIN 128 KP 128
    short* e2Wd = wpk + 32768;
    short* e2Wb = wpk + 49152;
    short* e2Wp = wpk + 65536;    // KIN 134 KP 160
    short* e2W2 = wpk + 86016;
    short* e3Wd = wpk + 102400;
    short* e3Wb = wpk + 118784;
    short* e3Wp = wpk + 135168;
    short* e3W2 = wpk + 155648;
    short* n1W1 = wpk + 172032;   // KIN 160 KP 160
    short* n1W2 = wpk + 192512;
    short* n2W1 = wpk + 208896;   // KIN 256 KP 256
    short* n2W2 = wpk + 241664;
    short* n3W1 = wpk + 258048;
    short* n3W2 = wpk + 290816;
    short* fW1  = wpk + 307200;   // KIN 384 NOUT 256
    short* fW2  = wpk + 405504;   // KIN 256
    const int packTotal = 438272;

    PackJobs pj;
    const float* pw[NPACK] = {
        c1_eW1, c1_eW1 + 32 * 128, c1_eW1 + 64 * 128, c1_eW2,
        c2_eW1, c2_eW1 + 128 * 128, c2_eW1 + 256 * 128, c2_eW2,
        c3_eW1, c3_eW1 + 128 * 128, c3_eW1 + 256 * 128, c3_eW2,
        c1_lW1, c1_lW2, c2_lW1, c2_lW2, c3_lW1, c3_lW2,
        fus_W1, fus_W2};
    const float* ps[NPACK] = {
        c1_eW1 + 32 * 128, nullptr, nullptr, nullptr,
        c2_eW1 + 128 * 128, nullptr, nullptr, nullptr,
        c3_eW1 + 128 * 128, nullptr, nullptr, nullptr,
        nullptr, nullptr, nullptr, nullptr, nullptr, nullptr,
        nullptr, nullptr};
    const int pk_kin[NPACK]  = {32, 32, 38, 128, 128, 128, 134, 128,
                                128, 128, 134, 128, 160, 128, 256, 128, 256, 128,
                                384, 256};
    const int pk_nout[NPACK] = {128, 128, 128, 128, 128, 128, 128, 128,
                                128, 128, 128, 128, 128, 128, 128, 128, 128, 128,
                                256, 128};
    const int pk_end[NPACK]  = {4096, 8192, 16384, 32768, 49152, 65536, 86016, 102400,
                                118784, 135168, 155648, 172032, 192512, 208896, 241664,
                                258048, 290816, 307200, 405504, 438272};
    for (int i = 0; i < NPACK; ++i) {
        pj.W[i] = pw[i]; pj.Wsub[i] = ps[i];
        pj.KIN[i] = pk_kin[i]; pj.NOUT[i] = pk_nout[i]; pj.end[i] = pk_end[i];
    }
    pack_all<<<(packTotal + 255) / 256, 256, 0, stream>>>(pj, wpk, packTotal);

    // ---- sort edges by dst ----
    const int eblk = (E + 255) / 256;
    hipMemsetAsync(cursor, 0, 25024 * sizeof(int), stream);
    hist_kernel<<<eblk, 256, 0, stream>>>(dstI, cursor, E);
    scan_kernel<<<1, 1024, 0, stream>>>(cursor, N);
    scatter_kernel<<<eblk, 256, 0, stream>>>(srcI, dstI, ea, cursor, sSrc, sDst, eaB, E);

    const int eblocks = (E + 127) / 128;
    const int nblocks = (N + 63) / 64;
    const int fblocks = (N + 31) / 32;
    const int swzQ = eblocks / 8, swzR = eblocks % 8;
    const size_t aggBytes = NP * sizeof(float);

    // ---- layer 1 (FIN=32) ----
    uv_pre<32, 40><<<nblocks, 256, 0, stream>>>(x, e1Wd, c1_eb1, e1Wb, uB, vB, sq, xB, N);
    hipMemsetAsync(agg, 0, aggBytes, stream);
    edge_conv4<32><<<eblocks, 256, 0, stream>>>(
        xB, sSrc, sDst, eaB, sq, uB, vB, e1Wp, e1W2, c1_eb2, agg, E, swzQ, swzR);
    node_mfma<32, 160, 168, false><<<nblocks, 256, 0, stream>>>(
        x, agg, n1W1, c1_lb1, n1W2, c1_lb2, x1, N);

    // ---- layer 2 (FIN=128, residual) ----
    uv_pre<128, 136><<<nblocks, 256, 0, stream>>>(x1, e2Wd, c2_eb1, e2Wb, uB, vB, sq, xB, N);
    hipMemsetAsync(agg, 0, aggBytes, stream);
    edge_conv4<128><<<eblocks, 256, 0, stream>>>(
        xB, sSrc, sDst, eaB, sq, uB, vB, e2Wp, e2W2, c2_eb2, agg, E, swzQ, swzR);
    node_mfma<128, 256, 264, true><<<nblocks, 256, 0, stream>>>(
        x1, agg, n2W1, c2_lb1, n2W2, c2_lb2, x2, N);

    // ---- layer 3 (FIN=128, residual) ----
    uv_pre<128, 136><<<nblocks, 256, 0, stream>>>(x2, e3Wd, c3_eb1, e3Wb, uB, vB, sq, xB, N);
    hipMemsetAsync(agg, 0, aggBytes, stream);
    edge_conv4<128><<<eblocks, 256, 0, stream>>>(
        xB, sSrc, sDst, eaB, sq, uB, vB, e3Wp, e3W2, c3_eb2, agg, E, swzQ, swzR);
    node_mfma<128, 256, 264, true><<<nblocks, 256, 0, stream>>>(
        x2, agg, n3W1, c3_lb1, n3W2, c3_lb2, x3, N);

    // ---- fusion ----
    fusion_mfma<<<fblocks, 128, 0, stream>>>(
        x1, x2, x3, fW1, fus_b1, fW2, fus_b2, (float*)d_out, N);
}

// Round 7
// 689.835 us; speedup vs baseline: 1.2399x; 1.2399x over previous
//
#include <hip/hip_runtime.h>
#include <math.h>

#define DEV __device__ __forceinline__

typedef __attribute__((ext_vector_type(8))) short bf16x8;
typedef __attribute__((ext_vector_type(4))) float f32x4;

DEV short f2bf(float v) {
    union { float f; unsigned u; } c; c.f = v;
    unsigned r = c.u + 0x7fffu + ((c.u >> 16) & 1u);   // RNE
    return (short)(r >> 16);
}
DEV float bf2f(short s) {
    return __uint_as_float(((unsigned)(unsigned short)s) << 16);
}

// ===========================================================================
// Weight packing: W [KIN][NOUT] f32 (optionally minus Wsub) -> bf16 MFMA-B
// fragments. layout: out[ks*(NOUT*32) + n*32 + kg*8 + i] = W[ks*32+kg*8+i][n]
// ===========================================================================
#define NPACK 17
struct PackJobs {
    const float* W[NPACK];
    const float* Wsub[NPACK];
    int KIN[NPACK];
    int NOUT[NPACK];
    int end[NPACK];
};

__global__ __launch_bounds__(256)
void pack_all(PackJobs j, short* __restrict__ out, int total)
{
    const int idx = blockIdx.x * 256 + threadIdx.x;
    if (idx >= total) return;
    int job = 0;
    while (idx >= j.end[job]) ++job;
    const int base = job ? j.end[job - 1] : 0;
    const int w = idx - base;
    const int nout = j.NOUT[job];
    const int per_ks = nout * 32;
    const int ks = w / per_ks;
    const int r  = w - ks * per_ks;
    const int n  = r >> 5;
    const int kg = (r >> 3) & 3;
    const int i  = r & 7;
    const int k  = ks * 32 + kg * 8 + i;
    float val = 0.0f;
    if (k < j.KIN[job]) {
        val = j.W[job][(size_t)k * nout + n];
        if (j.Wsub[job]) val -= j.Wsub[job][(size_t)k * nout + n];
    }
    out[idx] = f2bf(val);
}

// ===========================================================================
// Sorting by dst: histogram -> single-block scan -> scatter
// ===========================================================================
__global__ __launch_bounds__(256)
void hist_kernel(const int* __restrict__ dst, int* __restrict__ cnt, int E)
{
    const int e = blockIdx.x * 256 + threadIdx.x;
    if (e < E) atomicAdd(&cnt[dst[e]], 1);
}

__global__ __launch_bounds__(1024)
void scan_kernel(int* __restrict__ cnt, int NB)
{
    __shared__ int part[1024];
    const int t = threadIdx.x;
    const int CH = (NB + 1023) >> 10;
    const int base = t * CH;
    int s = 0;
    for (int k = 0; k < CH; ++k) { const int i = base + k; if (i < NB) s += cnt[i]; }
    part[t] = s;
    __syncthreads();
    for (int off = 1; off < 1024; off <<= 1) {
        const int add = (t >= off) ? part[t - off] : 0;
        __syncthreads();
        part[t] += add;
        __syncthreads();
    }
    int run = part[t] - s;
    for (int k = 0; k < CH; ++k) {
        const int i = base + k;
        if (i < NB) { const int c = cnt[i]; cnt[i] = run; run += c; }
    }
}

__global__ __launch_bounds__(256)
void scatter_kernel(const int* __restrict__ src, const int* __restrict__ dst,
                    const float* __restrict__ ea, int* __restrict__ cursor,
                    int* __restrict__ sSrc, int* __restrict__ sDst,
                    short* __restrict__ eaB, int E)
{
    const int e = blockIdx.x * 256 + threadIdx.x;
    if (e >= E) return;
    const int d = dst[e];
    const int p = atomicAdd(&cursor[d], 1);
    sSrc[p] = src[e];
    sDst[p] = d;
    const float4 a = ((const float4*)ea)[e];
    *(short4*)(eaB + (size_t)p * 4) =
        make_short4(f2bf(a.x), f2bf(a.y), f2bf(a.z), f2bf(a.w));
}

// ===========================================================================
// MFMA GEMM over an LDS row-tile (pre / node / fusion): wave = 16 rows x 128
// ===========================================================================
template<int KP, int FSTR, int NOUT, bool BIAS>
DEV void mfma_gemm(const short* aLds, const short* __restrict__ Wpk,
                   const float* __restrict__ b, int row0, int c0, int lane,
                   f32x4 (&acc)[8])
{
    const int l15 = lane & 15;
    const int lg  = lane >> 4;
#pragma unroll
    for (int f = 0; f < 8; ++f) {
        if (BIAS) {
            const float bv = b[c0 + f * 16 + l15];
            acc[f] = (f32x4){bv, bv, bv, bv};
        } else {
            acc[f] = (f32x4){0.f, 0.f, 0.f, 0.f};
        }
    }
    const short* arow  = aLds + (row0 + l15) * FSTR + lg * 8;
    const short* wbase = Wpk + (size_t)(c0 + l15) * 32 + lg * 8;
#pragma unroll
    for (int ks = 0; ks < KP / 32; ++ks) {
        const bf16x8 av = *(const bf16x8*)(arow + ks * 32);
        const short* wp = wbase + (size_t)ks * NOUT * 32;
#pragma unroll
        for (int f = 0; f < 8; ++f) {
            const bf16x8 bv = *(const bf16x8*)(wp + f * 512);
            acc[f] = __builtin_amdgcn_mfma_f32_16x16x32_bf16(av, bv, acc[f], 0, 0, 0);
        }
    }
}

// relu(acc [+ lds]) -> packed bf16 rows in LDS
template<int OSTR, bool ADDLDS>
DEV void pack_relu(const f32x4 (&acc)[8], short* out, int row0, int c0, int lane)
{
    const int l15 = lane & 15;
    const int lg  = lane >> 4;
#pragma unroll
    for (int f = 0; f < 8; ++f)
#pragma unroll
        for (int i = 0; i < 4; ++i) {
            const int row = row0 + lg * 4 + i;
            const int col = c0 + f * 16 + l15;
            float vv = acc[f][i];
            if (ADDLDS) vv += bf2f(out[row * OSTR + col]);
            vv = fmaxf(vv, 0.0f);
            const float o = __shfl_xor(vv, 1);
            if (!(lane & 1)) {
                const unsigned pk = ((unsigned)(unsigned short)f2bf(o) << 16) |
                                    (unsigned)(unsigned short)f2bf(vv);
                *(unsigned*)&out[row * OSTR + col] = pk;
            }
        }
}

// acc -> bf16 global rows (paired 4-byte stores)
DEV void store_bf16(const f32x4 (&acc)[8], short* __restrict__ out,
                    int n0, int wave, int lane, int N)
{
    const int l15 = lane & 15;
    const int lg  = lane >> 4;
#pragma unroll
    for (int f = 0; f < 8; ++f)
#pragma unroll
        for (int i = 0; i < 4; ++i) {
            const float vv = acc[f][i];
            const float o = __shfl_xor(vv, 1);
            if (!(lane & 1)) {
                const unsigned pk = ((unsigned)(unsigned short)f2bf(o) << 16) |
                                    (unsigned)(unsigned short)f2bf(vv);
                const int n = n0 + wave * 16 + lg * 4 + i;
                if (n < N)
                    *(unsigned*)&out[(size_t)n * 128 + f * 16 + l15] = pk;
            }
        }
}

// ===========================================================================
// Per-node precompute: u = x@(W1a-W1b)+b1 (bf16), sq = ||x||^2, xB bf16 copy.
// ===========================================================================
template<int FIN, int FSTR>
__global__ __launch_bounds__(256)
void pre_kernel(const float* __restrict__ xin,
                const short* __restrict__ Wd, const float* __restrict__ b1,
                short* __restrict__ uB, float* __restrict__ sq,
                short* __restrict__ xB, int N)
{
    __shared__ __align__(16) short feat[64 * FSTR];
    const int tid = threadIdx.x, lane = tid & 63, wave = tid >> 6;
    const int n0 = blockIdx.x * 64;
    {
        const int r = tid >> 2, s = tid & 3, n = n0 + r;
        short* frow = feat + r * FSTR;
        if (n < N) {
            const float4* xr = (const float4*)(xin + (size_t)n * FIN);
            float ss = 0.f;
#pragma unroll
            for (int d4 = s; d4 < FIN / 4; d4 += 4) {
                const float4 a = xr[d4];
                ss += a.x * a.x + a.y * a.y + a.z * a.z + a.w * a.w;
                const short4 sv = make_short4(f2bf(a.x), f2bf(a.y), f2bf(a.z), f2bf(a.w));
                *(short4*)(frow + d4 * 4) = sv;
                *(short4*)(xB + (size_t)n * FIN + d4 * 4) = sv;
            }
            ss += __shfl_xor(ss, 1); ss += __shfl_xor(ss, 2);
            if (s == 0) sq[n] = ss;
        } else {
            for (int d = s * 4; d < FIN; d += 16) *(short4*)(frow + d) = make_short4(0, 0, 0, 0);
        }
    }
    asm volatile("s_waitcnt lgkmcnt(0)" ::: "memory");
    f32x4 acc[8];
    mfma_gemm<FIN, FSTR, 128, true>(feat, Wd, b1, wave * 16, 0, lane, acc);
    store_bf16(acc, uB, n0, wave, lane, N);
}

// ===========================================================================
// Edge conv v5: 64 edges/block, 4 waves COLUMN-SPLIT (wave w -> cols w*32..+31)
// feat = [xj(FIN), p(FIN), e1, e2, ea4, pad] (K = 2*FIN+6 -> KPF)
// h1 = relu(feat@W1ext + u[dst]); m = relu(h1@W2+b2)
// block run-max over sorted dst -> atomicMax (zero-skip).
// ===========================================================================
template<int FIN>
__global__ __launch_bounds__(256)
void edge_conv5(const short* __restrict__ xB,
                const int* __restrict__ sSrc, const int* __restrict__ sDst,
                const short* __restrict__ eaB, const float* __restrict__ sq,
                const short* __restrict__ uB,
                const short* __restrict__ W1pk, const short* __restrict__ W2pk,
                const float* __restrict__ b2,
                float* __restrict__ agg, int E, int swzQ, int swzR)
{
    constexpr int KPF  = (FIN == 32) ? 96 : 288;
    constexpr int FSTR = KPF + 8;
    constexpr int H1STR = 136;
    __shared__ __align__(16) short feat[64 * FSTR];
    __shared__ __align__(16) short h1s[64 * H1STR];
    __shared__ int dstv[64];
    const int tid = threadIdx.x, lane = tid & 63, wave = tid >> 6;
    const int l15 = lane & 15, lg = lane >> 4;
    int bid = blockIdx.x;
    {   // bijective XCD-chunk swizzle
        const int xcd = bid & 7, idx = bid >> 3;
        bid = (xcd < swzR ? xcd * (swzQ + 1)
                          : swzR * (swzQ + 1) + (xcd - swzR) * swzQ) + idx;
    }
    const int e0 = bid * 64;
    const int c0 = wave * 32;

    // ---- stage 1: gather x, build [xj, p, tail]; stage u[dst] (4 thr/edge) --
    {
        const int r = tid >> 2, s = tid & 3, e = e0 + r;
        short* frow = feat + r * FSTR;
        short* urow = h1s + r * H1STR;
        if (e < E) {
            const int si = sSrc[e], di = sDst[e];
            if (s == 0) dstv[r] = di;
            float sp = 0.f;
#pragma unroll
            for (int c = s; c < FIN / 8; c += 4) {
                const bf16x8 a = *(const bf16x8*)(xB + (size_t)si * FIN + c * 8);
                const bf16x8 b = *(const bf16x8*)(xB + (size_t)di * FIN + c * 8);
                bf16x8 p;
#pragma unroll
                for (int jj = 0; jj < 8; ++jj) {
                    const float pj = bf2f(a[jj]) * bf2f(b[jj]);
                    sp += pj;
                    p[jj] = f2bf(pj);
                }
                *(bf16x8*)(frow + c * 8) = a;          // xj
                *(bf16x8*)(frow + FIN + c * 8) = p;    // p = xj*xi
            }
            sp += __shfl_xor(sp, 1); sp += __shfl_xor(sp, 2);
            if (s == 0) {
                const float e1v = sqrtf(fmaxf(sq[si] + sq[di] - 2.f * sp, 0.f));
                *(short2*)(frow + 2 * FIN) = make_short2(f2bf(e1v), f2bf(sp));
            }
            if (s == 1) {
                const short4 ea = *(const short4*)(eaB + (size_t)e * 4);
                *(short2*)(frow + 2 * FIN + 2) = make_short2(ea.x, ea.y);
                *(short2*)(frow + 2 * FIN + 4) = make_short2(ea.z, ea.w);
            }
            for (int d = 2 * FIN + 6 + s; d < KPF; d += 4) frow[d] = 0;
#pragma unroll
            for (int c = s; c < 16; c += 4)
                *(bf16x8*)(urow + c * 8) =
                    *(const bf16x8*)(uB + (size_t)di * 128 + c * 8);
        } else {
            if (s == 0) dstv[r] = -1;
            for (int d = s * 4; d < KPF; d += 16) *(short4*)(frow + d) = make_short4(0, 0, 0, 0);
            for (int d = s * 4; d < 128; d += 16) *(short4*)(urow + d) = make_short4(0, 0, 0, 0);
        }
    }
    __syncthreads();

    // ---- GEMM1 (col-split): wave computes its 32 cols for all 64 rows ----
    f32x4 acc[4][2];
#pragma unroll
    for (int sb = 0; sb < 4; ++sb) {
        acc[sb][0] = (f32x4){0.f, 0.f, 0.f, 0.f};
        acc[sb][1] = (f32x4){0.f, 0.f, 0.f, 0.f};
    }
    {
        const short* wb = W1pk + (size_t)(c0 + l15) * 32 + lg * 8;
#pragma unroll
        for (int ks = 0; ks < KPF / 32; ++ks) {
            const short* wp = wb + (size_t)ks * 4096;
            const bf16x8 bv0 = *(const bf16x8*)(wp);
            const bf16x8 bv1 = *(const bf16x8*)(wp + 512);
#pragma unroll
            for (int sb = 0; sb < 4; ++sb) {
                const bf16x8 av =
                    *(const bf16x8*)(feat + (sb * 16 + l15) * FSTR + ks * 32 + lg * 8);
                acc[sb][0] = __builtin_amdgcn_mfma_f32_16x16x32_bf16(av, bv0, acc[sb][0], 0, 0, 0);
                acc[sb][1] = __builtin_amdgcn_mfma_f32_16x16x32_bf16(av, bv1, acc[sb][1], 0, 0, 0);
            }
        }
    }
    // h1 = relu(acc + u) -> bf16 LDS (own cols only)
#pragma unroll
    for (int sb = 0; sb < 4; ++sb)
#pragma unroll
        for (int f = 0; f < 2; ++f)
#pragma unroll
            for (int i = 0; i < 4; ++i) {
                const int row = sb * 16 + lg * 4 + i;
                const int col = c0 + f * 16 + l15;
                float vv = acc[sb][f][i] + bf2f(h1s[row * H1STR + col]);
                vv = fmaxf(vv, 0.0f);
                const float o = __shfl_xor(vv, 1);
                if (!(lane & 1)) {
                    const unsigned pk = ((unsigned)(unsigned short)f2bf(o) << 16) |
                                        (unsigned)(unsigned short)f2bf(vv);
                    *(unsigned*)&h1s[row * H1STR + col] = pk;
                }
            }
    __syncthreads();

    // ---- GEMM2 (col-split) ----
#pragma unroll
    for (int sb = 0; sb < 4; ++sb)
#pragma unroll
        for (int f = 0; f < 2; ++f) {
            const float bv = b2[c0 + f * 16 + l15];
            acc[sb][f] = (f32x4){bv, bv, bv, bv};
        }
    {
        const short* wb = W2pk + (size_t)(c0 + l15) * 32 + lg * 8;
#pragma unroll
        for (int ks = 0; ks < 4; ++ks) {
            const short* wp = wb + (size_t)ks * 4096;
            const bf16x8 bv0 = *(const bf16x8*)(wp);
            const bf16x8 bv1 = *(const bf16x8*)(wp + 512);
#pragma unroll
            for (int sb = 0; sb < 4; ++sb) {
                const bf16x8 av =
                    *(const bf16x8*)(h1s + (sb * 16 + l15) * H1STR + ks * 32 + lg * 8);
                acc[sb][0] = __builtin_amdgcn_mfma_f32_16x16x32_bf16(av, bv0, acc[sb][0], 0, 0, 0);
                acc[sb][1] = __builtin_amdgcn_mfma_f32_16x16x32_bf16(av, bv1, acc[sb][1], 0, 0, 0);
            }
        }
    }
    __syncthreads();             // all h1 reads done -> overlay mbuf on h1s

    // ---- m -> bf16 mbuf [64][132] ----
    short* mb = h1s;
#pragma unroll
    for (int sb = 0; sb < 4; ++sb)
#pragma unroll
        for (int f = 0; f < 2; ++f)
#pragma unroll
            for (int i = 0; i < 4; ++i) {
                const int row = sb * 16 + lg * 4 + i;
                const int col = c0 + f * 16 + l15;
                const float vv = fmaxf(acc[sb][f][i], 0.0f);
                const float o = __shfl_xor(vv, 1);
                if (!(lane & 1)) {
                    const unsigned pk = ((unsigned)(unsigned short)f2bf(o) << 16) |
                                        (unsigned)(unsigned short)f2bf(vv);
                    *(unsigned*)&mb[row * 132 + col] = pk;
                }
            }
    __syncthreads();

    // ---- stage 4: run-max over sorted dst, one atomic per (run,col) ----
    {
        const int c  = tid >> 1;
        const int rh = tid & 1;
        int cur = -1;
        float mx = 0.0f;
#pragma unroll 4
        for (int i2 = 0; i2 < 32; ++i2) {
            const int row = rh * 32 + i2;
            const int d = dstv[row];
            const float val = bf2f(mb[row * 132 + c]);
            if (d != cur) {
                if (cur >= 0 && mx > 0.f)
                    atomicMax((int*)agg + (size_t)cur * 128 + c, __float_as_int(mx));
                cur = d;
                mx = val;
            } else {
                mx = fmaxf(mx, val);
            }
        }
        if (cur >= 0 && mx > 0.f)
            atomicMax((int*)agg + (size_t)cur * 128 + c, __float_as_int(mx));
    }
}

// ===========================================================================
// Node MLP (MFMA, barrier-free): y = relu(relu([x,agg]@W1+b1)@W2+b2) (+x).
// ===========================================================================
template<int FIN, int KP, int FSTR, bool RES>
__global__ __launch_bounds__(256)
void node_mfma(const float* __restrict__ xin, const float* __restrict__ agg,
               const short* __restrict__ W1pk, const float* __restrict__ b1,
               const short* __restrict__ W2pk, const float* __restrict__ b2,
               float* __restrict__ out, int N)
{
    constexpr int H1STR = 136;
    __shared__ __align__(16) short sh[64 * FSTR + 64 * H1STR];
    short* feat = sh;
    short* h1s  = sh + 64 * FSTR;
    const int tid = threadIdx.x, lane = tid & 63, wave = tid >> 6;
    const int n0 = blockIdx.x * 64;

    {
        const int r = tid >> 2, s = tid & 3, n = n0 + r;
        short* frow = feat + r * FSTR;
        if (n < N) {
            const float4* xr = (const float4*)(xin + (size_t)n * FIN);
            const float4* ar = (const float4*)(agg + (size_t)n * 128);
#pragma unroll
            for (int d4 = s; d4 < FIN / 4; d4 += 4) {
                const float4 v = xr[d4];
                *(short4*)(frow + d4 * 4) = make_short4(f2bf(v.x), f2bf(v.y), f2bf(v.z), f2bf(v.w));
            }
#pragma unroll
            for (int d4 = s; d4 < 32; d4 += 4) {
                const float4 v = ar[d4];
                *(short4*)(frow + FIN + d4 * 4) = make_short4(f2bf(v.x), f2bf(v.y), f2bf(v.z), f2bf(v.w));
            }
        } else {
            for (int d = s * 4; d < KP; d += 16) *(short4*)(frow + d) = make_short4(0, 0, 0, 0);
        }
    }
    asm volatile("s_waitcnt lgkmcnt(0)" ::: "memory");

    f32x4 acc[8];
    mfma_gemm<KP, FSTR, 128, true>(feat, W1pk, b1, wave * 16, 0, lane, acc);
    pack_relu<H1STR, false>(acc, h1s, wave * 16, 0, lane);
    asm volatile("s_waitcnt lgkmcnt(0)" ::: "memory");
    mfma_gemm<128, H1STR, 128, true>(h1s, W2pk, b2, wave * 16, 0, lane, acc);
    {
        const int l15 = lane & 15, lg = lane >> 4;
#pragma unroll
        for (int f = 0; f < 8; ++f)
#pragma unroll
            for (int i = 0; i < 4; ++i) {
                const int n = n0 + wave * 16 + lg * 4 + i;
                if (n < N) {
                    const int c = f * 16 + l15;
                    float v = fmaxf(acc[f][i], 0.0f);
                    if (RES) v += xin[(size_t)n * 128 + c];
                    out[(size_t)n * 128 + c] = v;
                }
            }
    }
}

// ===========================================================================
// Fusion MLP (MFMA, barrier-free): out = relu(relu([x1,x2,x3]@W1+b1)@W2+b2).
// ===========================================================================
__global__ __launch_bounds__(128)
void fusion_mfma(const float* __restrict__ x1, const float* __restrict__ x2,
                 const float* __restrict__ x3,
                 const short* __restrict__ W1pk, const float* __restrict__ b1,
                 const short* __restrict__ W2pk, const float* __restrict__ b2,
                 float* __restrict__ out, int N)
{
    constexpr int FSTR = 392;
    constexpr int H1STR = 264;
    __shared__ __align__(16) short sh[32 * FSTR + 32 * H1STR];
    short* feat = sh;
    short* h1s  = sh + 32 * FSTR;
    const int tid = threadIdx.x, lane = tid & 63, wave = tid >> 6;
    const int n0 = blockIdx.x * 32;

    {
        const int r = tid >> 2, s = tid & 3, n = n0 + r;
        short* frow = feat + r * FSTR;
        if (n < N) {
            const float4* a1 = (const float4*)(x1 + (size_t)n * 128);
            const float4* a2 = (const float4*)(x2 + (size_t)n * 128);
            const float4* a3 = (const float4*)(x3 + (size_t)n * 128);
#pragma unroll
            for (int d4 = s; d4 < 32; d4 += 4) {
                const float4 v1 = a1[d4], v2 = a2[d4], v3 = a3[d4];
                *(short4*)(frow + d4 * 4)       = make_short4(f2bf(v1.x), f2bf(v1.y), f2bf(v1.z), f2bf(v1.w));
                *(short4*)(frow + 128 + d4 * 4) = make_short4(f2bf(v2.x), f2bf(v2.y), f2bf(v2.z), f2bf(v2.w));
                *(short4*)(frow + 256 + d4 * 4) = make_short4(f2bf(v3.x), f2bf(v3.y), f2bf(v3.z), f2bf(v3.w));
            }
        } else {
            for (int d = s * 4; d < 384; d += 16) *(short4*)(frow + d) = make_short4(0, 0, 0, 0);
        }
    }
    asm volatile("s_waitcnt lgkmcnt(0)" ::: "memory");

    f32x4 acc[8];
#pragma unroll
    for (int c0 = 0; c0 < 256; c0 += 128) {
        mfma_gemm<384, FSTR, 256, true>(feat, W1pk, b1, wave * 16, c0, lane, acc);
        pack_relu<H1STR, false>(acc, h1s, wave * 16, c0, lane);
    }
    asm volatile("s_waitcnt lgkmcnt(0)" ::: "memory");
    mfma_gemm<256, H1STR, 128, true>(h1s, W2pk, b2, wave * 16, 0, lane, acc);
    {
        const int l15 = lane & 15, lg = lane >> 4;
#pragma unroll
        for (int f = 0; f < 8; ++f)
#pragma unroll
            for (int i = 0; i < 4; ++i) {
                const int n = n0 + wave * 16 + lg * 4 + i;
                if (n < N)
                    out[(size_t)n * 128 + f * 16 + l15] = fmaxf(acc[f][i], 0.0f);
            }
    }
}

// ===========================================================================
extern "C" void kernel_launch(void* const* d_in, const int* in_sizes, int n_in,
                              void* d_out, int out_size, void* d_ws, size_t ws_size,
                              hipStream_t stream)
{
    const float* x    = (const float*)d_in[0];
    const int*   eidx = (const int*)d_in[1];
    const float* ea   = (const float*)d_in[2];

    const float* c1_eW1 = (const float*)d_in[3];
    const float* c1_eb1 = (const float*)d_in[4];
    const float* c1_eW2 = (const float*)d_in[5];
    const float* c1_eb2 = (const float*)d_in[6];
    const float* c1_lW1 = (const float*)d_in[7];
    const float* c1_lb1 = (const float*)d_in[8];
    const float* c1_lW2 = (const float*)d_in[9];
    const float* c1_lb2 = (const float*)d_in[10];

    const float* c2_eW1 = (const float*)d_in[11];
    const float* c2_eb1 = (const float*)d_in[12];
    const float* c2_eW2 = (const float*)d_in[13];
    const float* c2_eb2 = (const float*)d_in[14];
    const float* c2_lW1 = (const float*)d_in[15];
    const float* c2_lb1 = (const float*)d_in[16];
    const float* c2_lW2 = (const float*)d_in[17];
    const float* c2_lb2 = (const float*)d_in[18];

    const float* c3_eW1 = (const float*)d_in[19];
    const float* c3_eb1 = (const float*)d_in[20];
    const float* c3_eW2 = (const float*)d_in[21];
    const float* c3_eb2 = (const float*)d_in[22];
    const float* c3_lW1 = (const float*)d_in[23];
    const float* c3_lb1 = (const float*)d_in[24];
    const float* c3_lW2 = (const float*)d_in[25];
    const float* c3_lb2 = (const float*)d_in[26];

    const float* fus_W1 = (const float*)d_in[27];
    const float* fus_b1 = (const float*)d_in[28];
    const float* fus_W2 = (const float*)d_in[29];
    const float* fus_b2 = (const float*)d_in[30];

    const int N = in_sizes[0] / 32;   // 25000
    const int E = in_sizes[1] / 2;    // 400000
    const int* srcI = eidx;
    const int* dstI = eidx + E;

    const size_t NP = (size_t)N * 128;
    float* ws  = (float*)d_ws;
    float* x1  = ws;
    float* x2  = x1 + NP;
    float* x3  = x2 + NP;
    float* agg = x3 + NP;
    float* sq  = agg + NP;
    int* cursor = (int*)(sq + N);
    int* sSrc   = cursor + 25024;
    int* sDst   = sSrc + E;
    short* eaB  = (short*)(sDst + E);
    short* uB   = eaB + (size_t)E * 4;
    short* xB   = uB + NP;
    short* wpk  = xB + NP;

    // packed-weight offsets (shorts)
    short* e1Wd = wpk + 0;        // KIN 32  KP 32   (W1a-W1b, layer1)
    short* e1Wx = wpk + 4096;     // KIN 70  KP 96   (eW1 rows [32,102): W1b|W1p|tail)
    short* e1W2 = wpk + 16384;    // KIN 128 KP 128
    short* e2Wd = wpk + 32768;    // KIN 128 KP 128
    short* e2Wx = wpk + 49152;    // KIN 262 KP 288  (rows [128,390))
    short* e2W2 = wpk + 86016;
    short* e3Wd = wpk + 102400;
    short* e3Wx = wpk + 118784;
    short* e3W2 = wpk + 155648;
    short* n1W1 = wpk + 172032;   // KIN 160 KP 160
    short* n1W2 = wpk + 192512;
    short* n2W1 = wpk + 208896;   // KIN 256 KP 256
    short* n2W2 = wpk + 241664;
    short* n3W1 = wpk + 258048;
    short* n3W2 = wpk + 290816;
    short* fW1  = wpk + 307200;   // KIN 384 NOUT 256
    short* fW2  = wpk + 405504;   // KIN 256
    const int packTotal = 438272;

    PackJobs pj;
    const float* pw[NPACK] = {
        c1_eW1, c1_eW1 + 32 * 128, c1_eW2,
        c2_eW1, c2_eW1 + 128 * 128, c2_eW2,
        c3_eW1, c3_eW1 + 128 * 128, c3_eW2,
        c1_lW1, c1_lW2, c2_lW1, c2_lW2, c3_lW1, c3_lW2,
        fus_W1, fus_W2};
    const float* ps[NPACK] = {
        c1_eW1 + 32 * 128, nullptr, nullptr,
        c2_eW1 + 128 * 128, nullptr, nullptr,
        c3_eW1 + 128 * 128, nullptr, nullptr,
        nullptr, nullptr, nullptr, nullptr, nullptr, nullptr,
        nullptr, nullptr};
    const int pk_kin[NPACK]  = {32, 70, 128, 128, 262, 128, 128, 262, 128,
                                160, 128, 256, 128, 256, 128, 384, 256};
    const int pk_nout[NPACK] = {128, 128, 128, 128, 128, 128, 128, 128, 128,
                                128, 128, 128, 128, 128, 128, 256, 128};
    const int pk_end[NPACK]  = {4096, 16384, 32768, 49152, 86016, 102400,
                                118784, 155648, 172032, 192512, 208896, 241664,
                                258048, 290816, 307200, 405504, 438272};
    for (int i = 0; i < NPACK; ++i) {
        pj.W[i] = pw[i]; pj.Wsub[i] = ps[i];
        pj.KIN[i] = pk_kin[i]; pj.NOUT[i] = pk_nout[i]; pj.end[i] = pk_end[i];
    }
    pack_all<<<(packTotal + 255) / 256, 256, 0, stream>>>(pj, wpk, packTotal);

    // ---- sort edges by dst ----
    const int eblk = (E + 255) / 256;
    hipMemsetAsync(cursor, 0, 25024 * sizeof(int), stream);
    hist_kernel<<<eblk, 256, 0, stream>>>(dstI, cursor, E);
    scan_kernel<<<1, 1024, 0, stream>>>(cursor, N);
    scatter_kernel<<<eblk, 256, 0, stream>>>(srcI, dstI, ea, cursor, sSrc, sDst, eaB, E);

    const int eblocks = (E + 63) / 64;
    const int nblocks = (N + 63) / 64;
    const int fblocks = (N + 31) / 32;
    const int swzQ = eblocks / 8, swzR = eblocks % 8;
    const size_t aggBytes = NP * sizeof(float);

    // ---- layer 1 (FIN=32) ----
    pre_kernel<32, 40><<<nblocks, 256, 0, stream>>>(x, e1Wd, c1_eb1, uB, sq, xB, N);
    hipMemsetAsync(agg, 0, aggBytes, stream);
    edge_conv5<32><<<eblocks, 256, 0, stream>>>(
        xB, sSrc, sDst, eaB, sq, uB, e1Wx, e1W2, c1_eb2, agg, E, swzQ, swzR);
    node_mfma<32, 160, 168, false><<<nblocks, 256, 0, stream>>>(
        x, agg, n1W1, c1_lb1, n1W2, c1_lb2, x1, N);

    // ---- layer 2 (FIN=128, residual) ----
    pre_kernel<128, 136><<<nblocks, 256, 0, stream>>>(x1, e2Wd, c2_eb1, uB, sq, xB, N);
    hipMemsetAsync(agg, 0, aggBytes, stream);
    edge_conv5<128><<<eblocks, 256, 0, stream>>>(
        xB, sSrc, sDst, eaB, sq, uB, e2Wx, e2W2, c2_eb2, agg, E, swzQ, swzR);
    node_mfma<128, 256, 264, true><<<nblocks, 256, 0, stream>>>(
        x1, agg, n2W1, c2_lb1, n2W2, c2_lb2, x2, N);

    // ---- layer 3 (FIN=128, residual) ----
    pre_kernel<128, 136><<<nblocks, 256, 0, stream>>>(x2, e3Wd, c3_eb1, uB, sq, xB, N);
    hipMemsetAsync(agg, 0, aggBytes, stream);
    edge_conv5<128><<<eblocks, 256, 0, stream>>>(
        xB, sSrc, sDst, eaB, sq, uB, e3Wx, e3W2, c3_eb2, agg, E, swzQ, swzR);
    node_mfma<128, 256, 264, true><<<nblocks, 256, 0, stream>>>(
        x2, agg, n3W1, c3_lb1, n3W2, c3_lb2, x3, N);

    // ---- fusion ----
    fusion_mfma<<<fblocks, 128, 0, stream>>>(
        x1, x2, x3, fW1, fus_b1, fW2, fus_b2, (float*)d_out, N);
}

// Round 8
// 597.018 us; speedup vs baseline: 1.4326x; 1.1555x over previous
//
#include <hip/hip_runtime.h>
#include <math.h>

#define DEV __device__ __forceinline__

typedef __attribute__((ext_vector_type(8))) short bf16x8;
typedef __attribute__((ext_vector_type(4))) float f32x4;

DEV short f2bf(float v) {
    union { float f; unsigned u; } c; c.f = v;
    unsigned r = c.u + 0x7fffu + ((c.u >> 16) & 1u);   // RNE
    return (short)(r >> 16);
}
DEV float bf2f(short s) {
    return __uint_as_float(((unsigned)(unsigned short)s) << 16);
}

// ===========================================================================
// Weight packing: W [KIN][NOUT] f32 (optionally minus Wsub) -> bf16 MFMA-B
// fragments. layout: out[ks*(NOUT*32) + n*32 + kg*8 + i] = W[ks*32+kg*8+i][n]
// ===========================================================================
#define NPACK 20
struct PackJobs {
    const float* W[NPACK];
    const float* Wsub[NPACK];
    int KIN[NPACK];
    int NOUT[NPACK];
    int end[NPACK];
};

__global__ __launch_bounds__(256)
void pack_all(PackJobs j, short* __restrict__ out, int total)
{
    const int idx = blockIdx.x * 256 + threadIdx.x;
    if (idx >= total) return;
    int job = 0;
    while (idx >= j.end[job]) ++job;
    const int base = job ? j.end[job - 1] : 0;
    const int w = idx - base;
    const int nout = j.NOUT[job];
    const int per_ks = nout * 32;
    const int ks = w / per_ks;
    const int r  = w - ks * per_ks;
    const int n  = r >> 5;
    const int kg = (r >> 3) & 3;
    const int i  = r & 7;
    const int k  = ks * 32 + kg * 8 + i;
    float val = 0.0f;
    if (k < j.KIN[job]) {
        val = j.W[job][(size_t)k * nout + n];
        if (j.Wsub[job]) val -= j.Wsub[job][(size_t)k * nout + n];
    }
    out[idx] = f2bf(val);
}

// ===========================================================================
// Sorting by dst: histogram -> single-block scan -> scatter
// ===========================================================================
__global__ __launch_bounds__(256)
void hist_kernel(const int* __restrict__ dst, int* __restrict__ cnt, int E)
{
    const int e = blockIdx.x * 256 + threadIdx.x;
    if (e < E) atomicAdd(&cnt[dst[e]], 1);
}

__global__ __launch_bounds__(1024)
void scan_kernel(int* __restrict__ cnt, int NB)
{
    __shared__ int part[1024];
    const int t = threadIdx.x;
    const int CH = (NB + 1023) >> 10;
    const int base = t * CH;
    int s = 0;
    for (int k = 0; k < CH; ++k) { const int i = base + k; if (i < NB) s += cnt[i]; }
    part[t] = s;
    __syncthreads();
    for (int off = 1; off < 1024; off <<= 1) {
        const int add = (t >= off) ? part[t - off] : 0;
        __syncthreads();
        part[t] += add;
        __syncthreads();
    }
    int run = part[t] - s;
    for (int k = 0; k < CH; ++k) {
        const int i = base + k;
        if (i < NB) { const int c = cnt[i]; cnt[i] = run; run += c; }
    }
}

__global__ __launch_bounds__(256)
void scatter_kernel(const int* __restrict__ src, const int* __restrict__ dst,
                    const float* __restrict__ ea, int* __restrict__ cursor,
                    int* __restrict__ sSrc, int* __restrict__ sDst,
                    short* __restrict__ eaB, int E)
{
    const int e = blockIdx.x * 256 + threadIdx.x;
    if (e >= E) return;
    const int d = dst[e];
    const int p = atomicAdd(&cursor[d], 1);
    sSrc[p] = src[e];
    sDst[p] = d;
    const float4 a = ((const float4*)ea)[e];
    *(short4*)(eaB + (size_t)p * 4) =
        make_short4(f2bf(a.x), f2bf(a.y), f2bf(a.z), f2bf(a.w));
}

// ===========================================================================
// MFMA GEMM over an LDS row-tile (pre / node / fusion): wave = 16 rows x 128
// ===========================================================================
template<int KP, int FSTR, int NOUT, bool BIAS>
DEV void mfma_gemm(const short* aLds, const short* __restrict__ Wpk,
                   const float* __restrict__ b, int row0, int c0, int lane,
                   f32x4 (&acc)[8])
{
    const int l15 = lane & 15;
    const int lg  = lane >> 4;
#pragma unroll
    for (int f = 0; f < 8; ++f) {
        if (BIAS) {
            const float bv = b[c0 + f * 16 + l15];
            acc[f] = (f32x4){bv, bv, bv, bv};
        } else {
            acc[f] = (f32x4){0.f, 0.f, 0.f, 0.f};
        }
    }
    const short* arow  = aLds + (row0 + l15) * FSTR + lg * 8;
    const short* wbase = Wpk + (size_t)(c0 + l15) * 32 + lg * 8;
#pragma unroll
    for (int ks = 0; ks < KP / 32; ++ks) {
        const bf16x8 av = *(const bf16x8*)(arow + ks * 32);
        const short* wp = wbase + (size_t)ks * NOUT * 32;
#pragma unroll
        for (int f = 0; f < 8; ++f) {
            const bf16x8 bv = *(const bf16x8*)(wp + f * 512);
            acc[f] = __builtin_amdgcn_mfma_f32_16x16x32_bf16(av, bv, acc[f], 0, 0, 0);
        }
    }
}

// relu(acc) -> packed bf16 rows in LDS
template<int OSTR>
DEV void pack_relu(const f32x4 (&acc)[8], short* out, int row0, int c0, int lane)
{
    const int l15 = lane & 15;
    const int lg  = lane >> 4;
#pragma unroll
    for (int f = 0; f < 8; ++f)
#pragma unroll
        for (int i = 0; i < 4; ++i) {
            const int row = row0 + lg * 4 + i;
            const int col = c0 + f * 16 + l15;
            float vv = fmaxf(acc[f][i], 0.0f);
            const float o = __shfl_xor(vv, 1);
            if (!(lane & 1)) {
                const unsigned pk = ((unsigned)(unsigned short)f2bf(o) << 16) |
                                    (unsigned)(unsigned short)f2bf(vv);
                *(unsigned*)&out[row * OSTR + col] = pk;
            }
        }
}

// acc -> bf16 global rows (paired 4-byte stores)
DEV void store_bf16(const f32x4 (&acc)[8], short* __restrict__ out,
                    int n0, int wave, int lane, int N)
{
    const int l15 = lane & 15;
    const int lg  = lane >> 4;
#pragma unroll
    for (int f = 0; f < 8; ++f)
#pragma unroll
        for (int i = 0; i < 4; ++i) {
            const float vv = acc[f][i];
            const float o = __shfl_xor(vv, 1);
            if (!(lane & 1)) {
                const unsigned pk = ((unsigned)(unsigned short)f2bf(o) << 16) |
                                    (unsigned)(unsigned short)f2bf(vv);
                const int n = n0 + wave * 16 + lg * 4 + i;
                if (n < N)
                    *(unsigned*)&out[(size_t)n * 128 + f * 16 + l15] = pk;
            }
        }
}

// ===========================================================================
// Per-node precompute: u = x@(W1a-W1b)+b1 (bf16), v = x@W1b (bf16),
// sq = ||x||^2, xB = bf16 copy of x.  Barrier-free (wave-local rows).
// ===========================================================================
template<int FIN, int FSTR>
__global__ __launch_bounds__(256)
void uv_pre(const float* __restrict__ xin,
            const short* __restrict__ Wd, const float* __restrict__ b1,
            const short* __restrict__ Wb,
            short* __restrict__ uB, short* __restrict__ vB,
            float* __restrict__ sq, short* __restrict__ xB, int N)
{
    __shared__ __align__(16) short feat[64 * FSTR];
    const int tid = threadIdx.x, lane = tid & 63, wave = tid >> 6;
    const int n0 = blockIdx.x * 64;
    {
        const int r = tid >> 2, s = tid & 3, n = n0 + r;
        short* frow = feat + r * FSTR;
        if (n < N) {
            const float4* xr = (const float4*)(xin + (size_t)n * FIN);
            float ss = 0.f;
#pragma unroll
            for (int d4 = s; d4 < FIN / 4; d4 += 4) {
                const float4 a = xr[d4];
                ss += a.x * a.x + a.y * a.y + a.z * a.z + a.w * a.w;
                const short4 sv = make_short4(f2bf(a.x), f2bf(a.y), f2bf(a.z), f2bf(a.w));
                *(short4*)(frow + d4 * 4) = sv;
                *(short4*)(xB + (size_t)n * FIN + d4 * 4) = sv;
            }
            ss += __shfl_xor(ss, 1); ss += __shfl_xor(ss, 2);
            if (s == 0) sq[n] = ss;
        } else {
            for (int d = s * 4; d < FIN; d += 16) *(short4*)(frow + d) = make_short4(0, 0, 0, 0);
        }
    }
    asm volatile("s_waitcnt lgkmcnt(0)" ::: "memory");
    f32x4 acc[8];
    mfma_gemm<FIN, FSTR, 128, true>(feat, Wd, b1, wave * 16, 0, lane, acc);
    store_bf16(acc, uB, n0, wave, lane, N);
    mfma_gemm<FIN, FSTR, 128, false>(feat, Wb, nullptr, wave * 16, 0, lane, acc);
    store_bf16(acc, vB, n0, wave, lane, N);
}

// ===========================================================================
// Edge conv v6: 64 edges/block, 4 waves COLUMN-SPLIT (wave w -> cols w*32..+31)
// feat = [p(FIN), e1, e2, ea4, pad] (K = FIN+6 -> KPP = FIN+32)
// uv = u[dst]+v[src] staged bf16 into h1s; h1 = relu(feat@Wp + uv);
// m = relu(h1@W2+b2); block run-max over sorted dst -> atomicMax (zero-skip).
// LDS ~38.7 KB -> 4 blocks/CU.
// ===========================================================================
template<int FIN>
__global__ __launch_bounds__(256)
void edge_conv6(const short* __restrict__ xB,
                const int* __restrict__ sSrc, const int* __restrict__ sDst,
                const short* __restrict__ eaB, const float* __restrict__ sq,
                const short* __restrict__ uB, const short* __restrict__ vB,
                const short* __restrict__ W1pk, const short* __restrict__ W2pk,
                const float* __restrict__ b2,
                float* __restrict__ agg, int E, int swzQ, int swzR)
{
    constexpr int KPP  = FIN + 32;       // 64 (F=32) / 160 (F=128)
    constexpr int FSTR = KPP + 8;        // 72 / 168 : 36/84 words, 2-way-free
    constexpr int H1STR = 132;           // 66 words = 2 mod 32, 2-way-free
    __shared__ __align__(16) short feat[64 * FSTR];
    __shared__ __align__(16) short h1s[64 * H1STR];
    __shared__ int dstv[64];
    const int tid = threadIdx.x, lane = tid & 63, wave = tid >> 6;
    const int l15 = lane & 15, lg = lane >> 4;
    int bid = blockIdx.x;
    {   // bijective XCD-chunk swizzle
        const int xcd = bid & 7, idx = bid >> 3;
        bid = (xcd < swzR ? xcd * (swzQ + 1)
                          : swzR * (swzQ + 1) + (xcd - swzR) * swzQ) + idx;
    }
    const int e0 = bid * 64;
    const int c0 = wave * 32;

    // ---- stage 1: p features + tail; stage uv = u[dst]+v[src] (4 thr/edge) --
    {
        const int r = tid >> 2, s = tid & 3, e = e0 + r;
        short* frow = feat + r * FSTR;
        short* urow = h1s + r * H1STR;
        if (e < E) {
            const int si = sSrc[e], di = sDst[e];
            if (s == 0) dstv[r] = di;
            float sp = 0.f;
#pragma unroll
            for (int c = s; c < FIN / 8; c += 4) {
                const bf16x8 a = *(const bf16x8*)(xB + (size_t)si * FIN + c * 8);
                const bf16x8 b = *(const bf16x8*)(xB + (size_t)di * FIN + c * 8);
                bf16x8 p;
#pragma unroll
                for (int jj = 0; jj < 8; ++jj) {
                    const float pj = bf2f(a[jj]) * bf2f(b[jj]);
                    sp += pj;
                    p[jj] = f2bf(pj);
                }
                *(bf16x8*)(frow + c * 8) = p;
            }
            sp += __shfl_xor(sp, 1); sp += __shfl_xor(sp, 2);
            if (s == 0) {
                const float e1v = sqrtf(fmaxf(sq[si] + sq[di] - 2.f * sp, 0.f));
                *(short2*)(frow + FIN) = make_short2(f2bf(e1v), f2bf(sp));
            }
            if (s == 1) {
                const short4 ea = *(const short4*)(eaB + (size_t)e * 4);
                *(short2*)(frow + FIN + 2) = make_short2(ea.x, ea.y);
                *(short2*)(frow + FIN + 4) = make_short2(ea.z, ea.w);
            }
            for (int d = FIN + 6 + s; d < KPP; d += 4) frow[d] = 0;
            // uv = u[dst] + v[src] (bf16 in, bf16 out) -> h1s row
#pragma unroll
            for (int c = s; c < 16; c += 4) {
                const bf16x8 uu = *(const bf16x8*)(uB + (size_t)di * 128 + c * 8);
                const bf16x8 vv = *(const bf16x8*)(vB + (size_t)si * 128 + c * 8);
                bf16x8 o;
#pragma unroll
                for (int jj = 0; jj < 8; ++jj)
                    o[jj] = f2bf(bf2f(uu[jj]) + bf2f(vv[jj]));
                *(bf16x8*)(urow + c * 8) = o;
            }
        } else {
            if (s == 0) dstv[r] = -1;
            for (int d = s * 4; d < KPP; d += 16) *(short4*)(frow + d) = make_short4(0, 0, 0, 0);
            for (int d = s * 4; d < 128; d += 16) *(short4*)(urow + d) = make_short4(0, 0, 0, 0);
        }
    }
    __syncthreads();

    // ---- GEMM1 (col-split): wave computes its 32 cols for all 64 rows ----
    f32x4 acc[4][2];
#pragma unroll
    for (int sb = 0; sb < 4; ++sb) {
        acc[sb][0] = (f32x4){0.f, 0.f, 0.f, 0.f};
        acc[sb][1] = (f32x4){0.f, 0.f, 0.f, 0.f};
    }
    {
        const short* wb = W1pk + (size_t)(c0 + l15) * 32 + lg * 8;
#pragma unroll
        for (int ks = 0; ks < KPP / 32; ++ks) {
            const short* wp = wb + (size_t)ks * 4096;
            const bf16x8 bv0 = *(const bf16x8*)(wp);
            const bf16x8 bv1 = *(const bf16x8*)(wp + 512);
#pragma unroll
            for (int sb = 0; sb < 4; ++sb) {
                const bf16x8 av =
                    *(const bf16x8*)(feat + (sb * 16 + l15) * FSTR + ks * 32 + lg * 8);
                acc[sb][0] = __builtin_amdgcn_mfma_f32_16x16x32_bf16(av, bv0, acc[sb][0], 0, 0, 0);
                acc[sb][1] = __builtin_amdgcn_mfma_f32_16x16x32_bf16(av, bv1, acc[sb][1], 0, 0, 0);
            }
        }
    }
    // h1 = relu(acc + uv) -> bf16 LDS (own cols only)
#pragma unroll
    for (int sb = 0; sb < 4; ++sb)
#pragma unroll
        for (int f = 0; f < 2; ++f)
#pragma unroll
            for (int i = 0; i < 4; ++i) {
                const int row = sb * 16 + lg * 4 + i;
                const int col = c0 + f * 16 + l15;
                float vv = acc[sb][f][i] + bf2f(h1s[row * H1STR + col]);
                vv = fmaxf(vv, 0.0f);
                const float o = __shfl_xor(vv, 1);
                if (!(lane & 1)) {
                    const unsigned pk = ((unsigned)(unsigned short)f2bf(o) << 16) |
                                        (unsigned)(unsigned short)f2bf(vv);
                    *(unsigned*)&h1s[row * H1STR + col] = pk;
                }
            }
    __syncthreads();

    // ---- GEMM2 (col-split) ----
#pragma unroll
    for (int sb = 0; sb < 4; ++sb)
#pragma unroll
        for (int f = 0; f < 2; ++f) {
            const float bv = b2[c0 + f * 16 + l15];
            acc[sb][f] = (f32x4){bv, bv, bv, bv};
        }
    {
        const short* wb = W2pk + (size_t)(c0 + l15) * 32 + lg * 8;
#pragma unroll
        for (int ks = 0; ks < 4; ++ks) {
            const short* wp = wb + (size_t)ks * 4096;
            const bf16x8 bv0 = *(const bf16x8*)(wp);
            const bf16x8 bv1 = *(const bf16x8*)(wp + 512);
#pragma unroll
            for (int sb = 0; sb < 4; ++sb) {
                const bf16x8 av =
                    *(const bf16x8*)(h1s + (sb * 16 + l15) * H1STR + ks * 32 + lg * 8);
                acc[sb][0] = __builtin_amdgcn_mfma_f32_16x16x32_bf16(av, bv0, acc[sb][0], 0, 0, 0);
                acc[sb][1] = __builtin_amdgcn_mfma_f32_16x16x32_bf16(av, bv1, acc[sb][1], 0, 0, 0);
            }
        }
    }
    __syncthreads();             // all h1 reads done -> reuse h1s as mbuf

    // ---- m -> bf16 mbuf (h1s, stride H1STR) ----
#pragma unroll
    for (int sb = 0; sb < 4; ++sb)
#pragma unroll
        for (int f = 0; f < 2; ++f)
#pragma unroll
            for (int i = 0; i < 4; ++i) {
                const int row = sb * 16 + lg * 4 + i;
                const int col = c0 + f * 16 + l15;
                const float vv = fmaxf(acc[sb][f][i], 0.0f);
                const float o = __shfl_xor(vv, 1);
                if (!(lane & 1)) {
                    const unsigned pk = ((unsigned)(unsigned short)f2bf(o) << 16) |
                                        (unsigned)(unsigned short)f2bf(vv);
                    *(unsigned*)&h1s[row * H1STR + col] = pk;
                }
            }
    __syncthreads();

    // ---- run-max over sorted dst, one atomic per (run,col), zero-skip ----
    {
        const int c  = tid >> 1;
        const int rh = tid & 1;
        int cur = -1;
        float mx = 0.0f;
#pragma unroll 4
        for (int i2 = 0; i2 < 32; ++i2) {
            const int row = rh * 32 + i2;
            const int d = dstv[row];
            const float val = bf2f(h1s[row * H1STR + c]);
            if (d != cur) {
                if (cur >= 0 && mx > 0.f)
                    atomicMax((int*)agg + (size_t)cur * 128 + c, __float_as_int(mx));
                cur = d;
                mx = val;
            } else {
                mx = fmaxf(mx, val);
            }
        }
        if (cur >= 0 && mx > 0.f)
            atomicMax((int*)agg + (size_t)cur * 128 + c, __float_as_int(mx));
    }
}

// ===========================================================================
// Node MLP (MFMA, barrier-free): y = relu(relu([x,agg]@W1+b1)@W2+b2) (+x).
// ===========================================================================
template<int FIN, int KP, int FSTR, bool RES>
__global__ __launch_bounds__(256)
void node_mfma(const float* __restrict__ xin, const float* __restrict__ agg,
               const short* __restrict__ W1pk, const float* __restrict__ b1,
               const short* __restrict__ W2pk, const float* __restrict__ b2,
               float* __restrict__ out, int N)
{
    constexpr int H1STR = 136;
    __shared__ __align__(16) short sh[64 * FSTR + 64 * H1STR];
    short* feat = sh;
    short* h1s  = sh + 64 * FSTR;
    const int tid = threadIdx.x, lane = tid & 63, wave = tid >> 6;
    const int n0 = blockIdx.x * 64;

    {
        const int r = tid >> 2, s = tid & 3, n = n0 + r;
        short* frow = feat + r * FSTR;
        if (n < N) {
            const float4* xr = (const float4*)(xin + (size_t)n * FIN);
            const float4* ar = (const float4*)(agg + (size_t)n * 128);
#pragma unroll
            for (int d4 = s; d4 < FIN / 4; d4 += 4) {
                const float4 v = xr[d4];
                *(short4*)(frow + d4 * 4) = make_short4(f2bf(v.x), f2bf(v.y), f2bf(v.z), f2bf(v.w));
            }
#pragma unroll
            for (int d4 = s; d4 < 32; d4 += 4) {
                const float4 v = ar[d4];
                *(short4*)(frow + FIN + d4 * 4) = make_short4(f2bf(v.x), f2bf(v.y), f2bf(v.z), f2bf(v.w));
            }
        } else {
            for (int d = s * 4; d < KP; d += 16) *(short4*)(frow + d) = make_short4(0, 0, 0, 0);
        }
    }
    asm volatile("s_waitcnt lgkmcnt(0)" ::: "memory");

    f32x4 acc[8];
    mfma_gemm<KP, FSTR, 128, true>(feat, W1pk, b1, wave * 16, 0, lane, acc);
    pack_relu<H1STR>(acc, h1s, wave * 16, 0, lane);
    asm volatile("s_waitcnt lgkmcnt(0)" ::: "memory");
    mfma_gemm<128, H1STR, 128, true>(h1s, W2pk, b2, wave * 16, 0, lane, acc);
    {
        const int l15 = lane & 15, lg = lane >> 4;
#pragma unroll
        for (int f = 0; f < 8; ++f)
#pragma unroll
            for (int i = 0; i < 4; ++i) {
                const int n = n0 + wave * 16 + lg * 4 + i;
                if (n < N) {
                    const int c = f * 16 + l15;
                    float v = fmaxf(acc[f][i], 0.0f);
                    if (RES) v += xin[(size_t)n * 128 + c];
                    out[(size_t)n * 128 + c] = v;
                }
            }
    }
}

// ===========================================================================
// Fusion MLP (MFMA, barrier-free): out = relu(relu([x1,x2,x3]@W1+b1)@W2+b2).
// ===========================================================================
__global__ __launch_bounds__(128)
void fusion_mfma(const float* __restrict__ x1, const float* __restrict__ x2,
                 const float* __restrict__ x3,
                 const short* __restrict__ W1pk, const float* __restrict__ b1,
                 const short* __restrict__ W2pk, const float* __restrict__ b2,
                 float* __restrict__ out, int N)
{
    constexpr int FSTR = 392;
    constexpr int H1STR = 264;
    __shared__ __align__(16) short sh[32 * FSTR + 32 * H1STR];
    short* feat = sh;
    short* h1s  = sh + 32 * FSTR;
    const int tid = threadIdx.x, lane = tid & 63, wave = tid >> 6;
    const int n0 = blockIdx.x * 32;

    {
        const int r = tid >> 2, s = tid & 3, n = n0 + r;
        short* frow = feat + r * FSTR;
        if (n < N) {
            const float4* a1 = (const float4*)(x1 + (size_t)n * 128);
            const float4* a2 = (const float4*)(x2 + (size_t)n * 128);
            const float4* a3 = (const float4*)(x3 + (size_t)n * 128);
#pragma unroll
            for (int d4 = s; d4 < 32; d4 += 4) {
                const float4 v1 = a1[d4], v2 = a2[d4], v3 = a3[d4];
                *(short4*)(frow + d4 * 4)       = make_short4(f2bf(v1.x), f2bf(v1.y), f2bf(v1.z), f2bf(v1.w));
                *(short4*)(frow + 128 + d4 * 4) = make_short4(f2bf(v2.x), f2bf(v2.y), f2bf(v2.z), f2bf(v2.w));
                *(short4*)(frow + 256 + d4 * 4) = make_short4(f2bf(v3.x), f2bf(v3.y), f2bf(v3.z), f2bf(v3.w));
            }
        } else {
            for (int d = s * 4; d < 384; d += 16) *(short4*)(frow + d) = make_short4(0, 0, 0, 0);
        }
    }
    asm volatile("s_waitcnt lgkmcnt(0)" ::: "memory");

    f32x4 acc[8];
#pragma unroll
    for (int c0 = 0; c0 < 256; c0 += 128) {
        mfma_gemm<384, FSTR, 256, true>(feat, W1pk, b1, wave * 16, c0, lane, acc);
        pack_relu<H1STR>(acc, h1s, wave * 16, c0, lane);
    }
    asm volatile("s_waitcnt lgkmcnt(0)" ::: "memory");
    mfma_gemm<256, H1STR, 128, true>(h1s, W2pk, b2, wave * 16, 0, lane, acc);
    {
        const int l15 = lane & 15, lg = lane >> 4;
#pragma unroll
        for (int f = 0; f < 8; ++f)
#pragma unroll
            for (int i = 0; i < 4; ++i) {
                const int n = n0 + wave * 16 + lg * 4 + i;
                if (n < N)
                    out[(size_t)n * 128 + f * 16 + l15] = fmaxf(acc[f][i], 0.0f);
            }
    }
}

// ===========================================================================
extern "C" void kernel_launch(void* const* d_in, const int* in_sizes, int n_in,
                              void* d_out, int out_size, void* d_ws, size_t ws_size,
                              hipStream_t stream)
{
    const float* x    = (const float*)d_in[0];
    const int*   eidx = (const int*)d_in[1];
    const float* ea   = (const float*)d_in[2];

    const float* c1_eW1 = (const float*)d_in[3];
    const float* c1_eb1 = (const float*)d_in[4];
    const float* c1_eW2 = (const float*)d_in[5];
    const float* c1_eb2 = (const float*)d_in[6];
    const float* c1_lW1 = (const float*)d_in[7];
    const float* c1_lb1 = (const float*)d_in[8];
    const float* c1_lW2 = (const float*)d_in[9];
    const float* c1_lb2 = (const float*)d_in[10];

    const float* c2_eW1 = (const float*)d_in[11];
    const float* c2_eb1 = (const float*)d_in[12];
    const float* c2_eW2 = (const float*)d_in[13];
    const float* c2_eb2 = (const float*)d_in[14];
    const float* c2_lW1 = (const float*)d_in[15];
    const float* c2_lb1 = (const float*)d_in[16];
    const float* c2_lW2 = (const float*)d_in[17];
    const float* c2_lb2 = (const float*)d_in[18];

    const float* c3_eW1 = (const float*)d_in[19];
    const float* c3_eb1 = (const float*)d_in[20];
    const float* c3_eW2 = (const float*)d_in[21];
    const float* c3_eb2 = (const float*)d_in[22];
    const float* c3_lW1 = (const float*)d_in[23];
    const float* c3_lb1 = (const float*)d_in[24];
    const float* c3_lW2 = (const float*)d_in[25];
    const float* c3_lb2 = (const float*)d_in[26];

    const float* fus_W1 = (const float*)d_in[27];
    const float* fus_b1 = (const float*)d_in[28];
    const float* fus_W2 = (const float*)d_in[29];
    const float* fus_b2 = (const float*)d_in[30];

    const int N = in_sizes[0] / 32;   // 25000
    const int E = in_sizes[1] / 2;    // 400000
    const int* srcI = eidx;
    const int* dstI = eidx + E;

    const size_t NP = (size_t)N * 128;
    float* ws  = (float*)d_ws;
    float* x1  = ws;
    float* x2  = x1 + NP;
    float* x3  = x2 + NP;
    float* agg = x3 + NP;
    float* sq  = agg + NP;
    int* cursor = (int*)(sq + N);
    int* sSrc   = cursor + 25024;
    int* sDst   = sSrc + E;
    short* eaB  = (short*)(sDst + E);
    short* uB   = eaB + (size_t)E * 4;
    short* vB   = uB + NP;
    short* xB   = vB + NP;
    short* wpk  = xB + NP;

    // packed-weight offsets (shorts)
    short* e1Wd = wpk + 0;        // KIN 32  KP 32   (W1a-W1b)
    short* e1Wb = wpk + 4096;     // KIN 32  KP 32   (W1b)
    short* e1Wp = wpk + 8192;     // KIN 38  KP 64   (p rows + e1,e2,ea)
    short* e1W2 = wpk + 16384;    // KIN 128 KP 128
    short* e2Wd = wpk + 32768;    // KIN 128 KP 128
    short* e2Wb = wpk + 49152;
    short* e2Wp = wpk + 65536;    // KIN 134 KP 160
    short* e2W2 = wpk + 86016;
    short* e3Wd = wpk + 102400;
    short* e3Wb = wpk + 118784;
    short* e3Wp = wpk + 135168;
    short* e3W2 = wpk + 155648;
    short* n1W1 = wpk + 172032;   // KIN 160 KP 160
    short* n1W2 = wpk + 192512;
    short* n2W1 = wpk + 208896;   // KIN 256 KP 256
    short* n2W2 = wpk + 241664;
    short* n3W1 = wpk + 258048;
    short* n3W2 = wpk + 290816;
    short* fW1  = wpk + 307200;   // KIN 384 NOUT 256
    short* fW2  = wpk + 405504;   // KIN 256
    const int packTotal = 438272;

    PackJobs pj;
    const float* pw[NPACK] = {
        c1_eW1, c1_eW1 + 32 * 128, c1_eW1 + 64 * 128, c1_eW2,
        c2_eW1, c2_eW1 + 128 * 128, c2_eW1 + 256 * 128, c2_eW2,
        c3_eW1, c3_eW1 + 128 * 128, c3_eW1 + 256 * 128, c3_eW2,
        c1_lW1, c1_lW2, c2_lW1, c2_lW2, c3_lW1, c3_lW2,
        fus_W1, fus_W2};
    const float* ps[NPACK] = {
        c1_eW1 + 32 * 128, nullptr, nullptr, nullptr,
        c2_eW1 + 128 * 128, nullptr, nullptr, nullptr,
        c3_eW1 + 128 * 128, nullptr, nullptr, nullptr,
        nullptr, nullptr, nullptr, nullptr, nullptr, nullptr,
        nullptr, nullptr};
    const int pk_kin[NPACK]  = {32, 32, 38, 128, 128, 128, 134, 128,
                                128, 128, 134, 128, 160, 128, 256, 128, 256, 128,
                                384, 256};
    const int pk_nout[NPACK] = {128, 128, 128, 128, 128, 128, 128, 128,
                                128, 128, 128, 128, 128, 128, 128, 128, 128, 128,
                                256, 128};
    const int pk_end[NPACK]  = {4096, 8192, 16384, 32768, 49152, 65536, 86016, 102400,
                                118784, 135168, 155648, 172032, 192512, 208896, 241664,
                                258048, 290816, 307200, 405504, 438272};
    for (int i = 0; i < NPACK; ++i) {
        pj.W[i] = pw[i]; pj.Wsub[i] = ps[i];
        pj.KIN[i] = pk_kin[i]; pj.NOUT[i] = pk_nout[i]; pj.end[i] = pk_end[i];
    }
    pack_all<<<(packTotal + 255) / 256, 256, 0, stream>>>(pj, wpk, packTotal);

    // ---- sort edges by dst ----
    const int eblk = (E + 255) / 256;
    hipMemsetAsync(cursor, 0, 25024 * sizeof(int), stream);
    hist_kernel<<<eblk, 256, 0, stream>>>(dstI, cursor, E);
    scan_kernel<<<1, 1024, 0, stream>>>(cursor, N);
    scatter_kernel<<<eblk, 256, 0, stream>>>(srcI, dstI, ea, cursor, sSrc, sDst, eaB, E);

    const int eblocks = (E + 63) / 64;
    const int nblocks = (N + 63) / 64;
    const int fblocks = (N + 31) / 32;
    const int swzQ = eblocks / 8, swzR = eblocks % 8;
    const size_t aggBytes = NP * sizeof(float);

    // ---- layer 1 (FIN=32) ----
    uv_pre<32, 40><<<nblocks, 256, 0, stream>>>(x, e1Wd, c1_eb1, e1Wb, uB, vB, sq, xB, N);
    hipMemsetAsync(agg, 0, aggBytes, stream);
    edge_conv6<32><<<eblocks, 256, 0, stream>>>(
        xB, sSrc, sDst, eaB, sq, uB, vB, e1Wp, e1W2, c1_eb2, agg, E, swzQ, swzR);
    node_mfma<32, 160, 168, false><<<nblocks, 256, 0, stream>>>(
        x, agg, n1W1, c1_lb1, n1W2, c1_lb2, x1, N);

    // ---- layer 2 (FIN=128, residual) ----
    uv_pre<128, 136><<<nblocks, 256, 0, stream>>>(x1, e2Wd, c2_eb1, e2Wb, uB, vB, sq, xB, N);
    hipMemsetAsync(agg, 0, aggBytes, stream);
    edge_conv6<128><<<eblocks, 256, 0, stream>>>(
        xB, sSrc, sDst, eaB, sq, uB, vB, e2Wp, e2W2, c2_eb2, agg, E, swzQ, swzR);
    node_mfma<128, 256, 264, true><<<nblocks, 256, 0, stream>>>(
        x1, agg, n2W1, c2_lb1, n2W2, c2_lb2, x2, N);

    // ---- layer 3 (FIN=128, residual) ----
    uv_pre<128, 136><<<nblocks, 256, 0, stream>>>(x2, e3Wd, c3_eb1, e3Wb, uB, vB, sq, xB, N);
    hipMemsetAsync(agg, 0, aggBytes, stream);
    edge_conv6<128><<<eblocks, 256, 0, stream>>>(
        xB, sSrc, sDst, eaB, sq, uB, vB, e3Wp, e3W2, c3_eb2, agg, E, swzQ, swzR);
    node_mfma<128, 256, 264, true><<<nblocks, 256, 0, stream>>>(
        x2, agg, n3W1, c3_lb1, n3W2, c3_lb2, x3, N);

    // ---- fusion ----
    fusion_mfma<<<fblocks, 128, 0, stream>>>(
        x1, x2, x3, fW1, fus_b1, fW2, fus_b2, (float*)d_out, N);
}

// Round 9
// 512.784 us; speedup vs baseline: 1.6680x; 1.1643x over previous
//
#include <hip/hip_runtime.h>
#include <math.h>

#define DEV __device__ __forceinline__

typedef __attribute__((ext_vector_type(8))) short bf16x8;
typedef __attribute__((ext_vector_type(4))) float f32x4;

DEV short f2bf(float v) {
    union { float f; unsigned u; } c; c.f = v;
    unsigned r = c.u + 0x7fffu + ((c.u >> 16) & 1u);   // RNE
    return (short)(r >> 16);
}
DEV float bf2f(short s) {
    return __uint_as_float(((unsigned)(unsigned short)s) << 16);
}
// 2x f32 -> packed bf16 in one VALU op (no builtin on gfx950; T12/m240)
DEV unsigned cvt_pk(float lo, float hi) {
    unsigned r;
    asm("v_cvt_pk_bf16_f32 %0, %1, %2" : "=v"(r) : "v"(lo), "v"(hi));
    return r;
}
DEV uint2 pk4(const float4 v) {
    uint2 r; r.x = cvt_pk(v.x, v.y); r.y = cvt_pk(v.z, v.w); return r;
}

// ===========================================================================
// Weight packing: W [KIN][NOUT] f32 (optionally minus Wsub) -> bf16 MFMA-B
// fragments. layout: out[ks*(NOUT*32) + n*32 + kg*8 + i] = W[ks*32+kg*8+i][n]
// ===========================================================================
#define NPACK 20
struct PackJobs {
    const float* W[NPACK];
    const float* Wsub[NPACK];
    int KIN[NPACK];
    int NOUT[NPACK];
    int end[NPACK];
};

__global__ __launch_bounds__(256)
void pack_all(PackJobs j, short* __restrict__ out, int total)
{
    const int idx = blockIdx.x * 256 + threadIdx.x;
    if (idx >= total) return;
    int job = 0;
    while (idx >= j.end[job]) ++job;
    const int base = job ? j.end[job - 1] : 0;
    const int w = idx - base;
    const int nout = j.NOUT[job];
    const int per_ks = nout * 32;
    const int ks = w / per_ks;
    const int r  = w - ks * per_ks;
    const int n  = r >> 5;
    const int kg = (r >> 3) & 3;
    const int i  = r & 7;
    const int k  = ks * 32 + kg * 8 + i;
    float val = 0.0f;
    if (k < j.KIN[job]) {
        val = j.W[job][(size_t)k * nout + n];
        if (j.Wsub[job]) val -= j.Wsub[job][(size_t)k * nout + n];
    }
    out[idx] = f2bf(val);
}

// ===========================================================================
// Sorting by dst: histogram -> single-block scan -> scatter
// ===========================================================================
__global__ __launch_bounds__(256)
void hist_kernel(const int* __restrict__ dst, int* __restrict__ cnt, int E)
{
    const int e = blockIdx.x * 256 + threadIdx.x;
    if (e < E) atomicAdd(&cnt[dst[e]], 1);
}

__global__ __launch_bounds__(1024)
void scan_kernel(int* __restrict__ cnt, int NB)
{
    __shared__ int part[1024];
    const int t = threadIdx.x;
    const int CH = (NB + 1023) >> 10;
    const int base = t * CH;
    int s = 0;
    for (int k = 0; k < CH; ++k) { const int i = base + k; if (i < NB) s += cnt[i]; }
    part[t] = s;
    __syncthreads();
    for (int off = 1; off < 1024; off <<= 1) {
        const int add = (t >= off) ? part[t - off] : 0;
        __syncthreads();
        part[t] += add;
        __syncthreads();
    }
    int run = part[t] - s;
    for (int k = 0; k < CH; ++k) {
        const int i = base + k;
        if (i < NB) { const int c = cnt[i]; cnt[i] = run; run += c; }
    }
}

__global__ __launch_bounds__(256)
void scatter_kernel(const int* __restrict__ src, const int* __restrict__ dst,
                    const float* __restrict__ ea, int* __restrict__ cursor,
                    int* __restrict__ sSrc, int* __restrict__ sDst,
                    short* __restrict__ eaB, int E)
{
    const int e = blockIdx.x * 256 + threadIdx.x;
    if (e >= E) return;
    const int d = dst[e];
    const int p = atomicAdd(&cursor[d], 1);
    sSrc[p] = src[e];
    sDst[p] = d;
    const float4 a = ((const float4*)ea)[e];
    *(uint2*)(eaB + (size_t)p * 4) = pk4(a);
}

// ===========================================================================
// MFMA GEMM over an LDS row-tile (pre / node / fusion): wave = 16 rows x 128
// ===========================================================================
template<int KP, int FSTR, int NOUT, bool BIAS>
DEV void mfma_gemm(const short* aLds, const short* __restrict__ Wpk,
                   const float* __restrict__ b, int row0, int c0, int lane,
                   f32x4 (&acc)[8])
{
    const int l15 = lane & 15;
    const int lg  = lane >> 4;
#pragma unroll
    for (int f = 0; f < 8; ++f) {
        if (BIAS) {
            const float bv = b[c0 + f * 16 + l15];
            acc[f] = (f32x4){bv, bv, bv, bv};
        } else {
            acc[f] = (f32x4){0.f, 0.f, 0.f, 0.f};
        }
    }
    const short* arow  = aLds + (row0 + l15) * FSTR + lg * 8;
    const short* wbase = Wpk + (size_t)(c0 + l15) * 32 + lg * 8;
#pragma unroll
    for (int ks = 0; ks < KP / 32; ++ks) {
        const bf16x8 av = *(const bf16x8*)(arow + ks * 32);
        const short* wp = wbase + (size_t)ks * NOUT * 32;
#pragma unroll
        for (int f = 0; f < 8; ++f) {
            const bf16x8 bv = *(const bf16x8*)(wp + f * 512);
            acc[f] = __builtin_amdgcn_mfma_f32_16x16x32_bf16(av, bv, acc[f], 0, 0, 0);
        }
    }
}

// relu(acc) -> packed bf16 rows in LDS
template<int OSTR>
DEV void pack_relu(const f32x4 (&acc)[8], short* out, int row0, int c0, int lane)
{
    const int l15 = lane & 15;
    const int lg  = lane >> 4;
#pragma unroll
    for (int f = 0; f < 8; ++f)
#pragma unroll
        for (int i = 0; i < 4; ++i) {
            const int row = row0 + lg * 4 + i;
            const int col = c0 + f * 16 + l15;
            const float vv = fmaxf(acc[f][i], 0.0f);
            const float o = __shfl_xor(vv, 1);
            if (!(lane & 1))
                *(unsigned*)&out[row * OSTR + col] = cvt_pk(vv, o);
        }
}

// acc -> bf16 global rows (paired 4-byte stores)
DEV void store_bf16(const f32x4 (&acc)[8], short* __restrict__ out,
                    int n0, int wave, int lane, int N)
{
    const int l15 = lane & 15;
    const int lg  = lane >> 4;
#pragma unroll
    for (int f = 0; f < 8; ++f)
#pragma unroll
        for (int i = 0; i < 4; ++i) {
            const float vv = acc[f][i];
            const float o = __shfl_xor(vv, 1);
            if (!(lane & 1)) {
                const int n = n0 + wave * 16 + lg * 4 + i;
                if (n < N)
                    *(unsigned*)&out[(size_t)n * 128 + f * 16 + l15] = cvt_pk(vv, o);
            }
        }
}

// ===========================================================================
// Per-node precompute: u = x@(W1a-W1b)+b1 (bf16), v = x@W1b (bf16),
// sq = ||x||^2, xB = bf16 copy of x.  Barrier-free (wave-local rows).
// ===========================================================================
template<int FIN, int FSTR>
__global__ __launch_bounds__(256)
void uv_pre(const float* __restrict__ xin,
            const short* __restrict__ Wd, const float* __restrict__ b1,
            const short* __restrict__ Wb,
            short* __restrict__ uB, short* __restrict__ vB,
            float* __restrict__ sq, short* __restrict__ xB, int N)
{
    __shared__ __align__(16) short feat[64 * FSTR];
    const int tid = threadIdx.x, lane = tid & 63, wave = tid >> 6;
    const int n0 = blockIdx.x * 64;
    {
        const int r = tid >> 2, s = tid & 3, n = n0 + r;
        short* frow = feat + r * FSTR;
        if (n < N) {
            const float4* xr = (const float4*)(xin + (size_t)n * FIN);
            float ss = 0.f;
#pragma unroll
            for (int d4 = s; d4 < FIN / 4; d4 += 4) {
                const float4 a = xr[d4];
                ss += a.x * a.x + a.y * a.y + a.z * a.z + a.w * a.w;
                const uint2 sv = pk4(a);
                *(uint2*)(frow + d4 * 4) = sv;
                *(uint2*)(xB + (size_t)n * FIN + d4 * 4) = sv;
            }
            ss += __shfl_xor(ss, 1); ss += __shfl_xor(ss, 2);
            if (s == 0) sq[n] = ss;
        } else {
            for (int d = s * 4; d < FIN; d += 16) *(short4*)(frow + d) = make_short4(0, 0, 0, 0);
        }
    }
    asm volatile("s_waitcnt lgkmcnt(0)" ::: "memory");
    f32x4 acc[8];
    mfma_gemm<FIN, FSTR, 128, true>(feat, Wd, b1, wave * 16, 0, lane, acc);
    store_bf16(acc, uB, n0, wave, lane, N);
    mfma_gemm<FIN, FSTR, 128, false>(feat, Wb, nullptr, wave * 16, 0, lane, acc);
    store_bf16(acc, vB, n0, wave, lane, N);
}

// ===========================================================================
// Edge conv v7: 64 edges/block, 512 threads, 8 waves COLUMN-SPLIT (16 cols/wave)
// feat = [p(FIN), e1, e2, ea4, pad] (K = FIN+32); uv = u[dst]+v[src] in h1s;
// h1 = relu(feat@Wp + uv); m = relu(h1@W2+b2);
// block run-max over sorted dst -> atomicMax (zero-skip).
// LDS ~39 KB -> 4 blocks/CU = 32 waves/CU.
// ===========================================================================
template<int FIN>
__global__ __launch_bounds__(512, 8)
void edge_conv7(const short* __restrict__ xB,
                const int* __restrict__ sSrc, const int* __restrict__ sDst,
                const short* __restrict__ eaB, const float* __restrict__ sq,
                const short* __restrict__ uB, const short* __restrict__ vB,
                const short* __restrict__ W1pk, const short* __restrict__ W2pk,
                const float* __restrict__ b2,
                float* __restrict__ agg, int E, int swzQ, int swzR)
{
    constexpr int KPP  = FIN + 32;       // 64 (F=32) / 160 (F=128)
    constexpr int FSTR = KPP + 8;        // 72 / 168
    constexpr int H1STR = 136;
    __shared__ __align__(16) short feat[64 * FSTR];
    __shared__ __align__(16) short h1s[64 * H1STR];
    __shared__ int dstv[64];
    const int tid = threadIdx.x, lane = tid & 63, wave = tid >> 6;
    const int l15 = lane & 15, lg = lane >> 4;
    int bid = blockIdx.x;
    {   // bijective XCD-chunk swizzle
        const int xcd = bid & 7, idx = bid >> 3;
        bid = (xcd < swzR ? xcd * (swzQ + 1)
                          : swzR * (swzQ + 1) + (xcd - swzR) * swzQ) + idx;
    }
    const int e0 = bid * 64;
    const int c0 = wave * 16;

    // ---- stage 1: p features + tail; uv = u[dst]+v[src] (8 thr/edge) ----
    {
        const int r = tid >> 3, s = tid & 7, e = e0 + r;
        short* frow = feat + r * FSTR;
        short* urow = h1s + r * H1STR;
        if (e < E) {
            const int si = sSrc[e], di = sDst[e];
            if (s == 0) dstv[r] = di;
            float sp = 0.f;
#pragma unroll
            for (int c = s; c < FIN / 8; c += 8) {
                const bf16x8 a = *(const bf16x8*)(xB + (size_t)si * FIN + c * 8);
                const bf16x8 b = *(const bf16x8*)(xB + (size_t)di * FIN + c * 8);
                float p[8];
#pragma unroll
                for (int jj = 0; jj < 8; ++jj) {
                    p[jj] = bf2f(a[jj]) * bf2f(b[jj]);
                    sp += p[jj];
                }
                uint4 w;
                w.x = cvt_pk(p[0], p[1]); w.y = cvt_pk(p[2], p[3]);
                w.z = cvt_pk(p[4], p[5]); w.w = cvt_pk(p[6], p[7]);
                *(uint4*)(frow + c * 8) = w;
            }
            sp += __shfl_xor(sp, 1); sp += __shfl_xor(sp, 2); sp += __shfl_xor(sp, 4);
            if (s == 0) {
                const float e1v = sqrtf(fmaxf(sq[si] + sq[di] - 2.f * sp, 0.f));
                *(unsigned*)(frow + FIN) = cvt_pk(e1v, sp);
            }
            if (s == 1) {
                const short4 ea = *(const short4*)(eaB + (size_t)e * 4);
                *(short2*)(frow + FIN + 2) = make_short2(ea.x, ea.y);
                *(short2*)(frow + FIN + 4) = make_short2(ea.z, ea.w);
            }
            for (int d = FIN + 6 + s; d < KPP; d += 8) frow[d] = 0;
            // uv = u[dst] + v[src] (bf16 in, bf16 out) -> h1s row
#pragma unroll
            for (int c = s; c < 16; c += 8) {
                const bf16x8 uu = *(const bf16x8*)(uB + (size_t)di * 128 + c * 8);
                const bf16x8 vv = *(const bf16x8*)(vB + (size_t)si * 128 + c * 8);
                float o[8];
#pragma unroll
                for (int jj = 0; jj < 8; ++jj)
                    o[jj] = bf2f(uu[jj]) + bf2f(vv[jj]);
                uint4 w;
                w.x = cvt_pk(o[0], o[1]); w.y = cvt_pk(o[2], o[3]);
                w.z = cvt_pk(o[4], o[5]); w.w = cvt_pk(o[6], o[7]);
                *(uint4*)(urow + c * 8) = w;
            }
        } else {
            if (s == 0) dstv[r] = -1;
            for (int d = s * 4; d < KPP; d += 32) *(short4*)(frow + d) = make_short4(0, 0, 0, 0);
            for (int d = s * 4; d < 128; d += 32) *(short4*)(urow + d) = make_short4(0, 0, 0, 0);
        }
    }
    __syncthreads();

    // ---- GEMM1 (col-split): wave computes its 16 cols for all 64 rows ----
    f32x4 acc[4];
#pragma unroll
    for (int sb = 0; sb < 4; ++sb) acc[sb] = (f32x4){0.f, 0.f, 0.f, 0.f};
    {
        const short* wb = W1pk + (size_t)(c0 + l15) * 32 + lg * 8;
#pragma unroll
        for (int ks = 0; ks < KPP / 32; ++ks) {
            const bf16x8 bv = *(const bf16x8*)(wb + (size_t)ks * 4096);
#pragma unroll
            for (int sb = 0; sb < 4; ++sb) {
                const bf16x8 av =
                    *(const bf16x8*)(feat + (sb * 16 + l15) * FSTR + ks * 32 + lg * 8);
                acc[sb] = __builtin_amdgcn_mfma_f32_16x16x32_bf16(av, bv, acc[sb], 0, 0, 0);
            }
        }
    }
    // h1 = relu(acc + uv) -> bf16 LDS (own cols only)
#pragma unroll
    for (int sb = 0; sb < 4; ++sb)
#pragma unroll
        for (int i = 0; i < 4; ++i) {
            const int row = sb * 16 + lg * 4 + i;
            const int col = c0 + l15;
            float vv = acc[sb][i] + bf2f(h1s[row * H1STR + col]);
            vv = fmaxf(vv, 0.0f);
            const float o = __shfl_xor(vv, 1);
            if (!(lane & 1))
                *(unsigned*)&h1s[row * H1STR + col] = cvt_pk(vv, o);
        }
    __syncthreads();

    // ---- GEMM2 (col-split) ----
    {
        const float bv0 = b2[c0 + l15];
#pragma unroll
        for (int sb = 0; sb < 4; ++sb) acc[sb] = (f32x4){bv0, bv0, bv0, bv0};
    }
    {
        const short* wb = W2pk + (size_t)(c0 + l15) * 32 + lg * 8;
#pragma unroll
        for (int ks = 0; ks < 4; ++ks) {
            const bf16x8 bv = *(const bf16x8*)(wb + (size_t)ks * 4096);
#pragma unroll
            for (int sb = 0; sb < 4; ++sb) {
                const bf16x8 av =
                    *(const bf16x8*)(h1s + (sb * 16 + l15) * H1STR + ks * 32 + lg * 8);
                acc[sb] = __builtin_amdgcn_mfma_f32_16x16x32_bf16(av, bv, acc[sb], 0, 0, 0);
            }
        }
    }
    __syncthreads();             // all h1 reads done -> reuse h1s as mbuf

    // ---- m -> bf16 mbuf (h1s, stride H1STR) ----
#pragma unroll
    for (int sb = 0; sb < 4; ++sb)
#pragma unroll
        for (int i = 0; i < 4; ++i) {
            const int row = sb * 16 + lg * 4 + i;
            const int col = c0 + l15;
            const float vv = fmaxf(acc[sb][i], 0.0f);
            const float o = __shfl_xor(vv, 1);
            if (!(lane & 1))
                *(unsigned*)&h1s[row * H1STR + col] = cvt_pk(vv, o);
        }
    __syncthreads();

    // ---- run-max over sorted dst (4 strips of 16 rows), zero-skip ----
    {
        const int c  = tid & 127;
        const int rh = tid >> 7;
        int cur = -1;
        float mx = 0.0f;
#pragma unroll 4
        for (int i2 = 0; i2 < 16; ++i2) {
            const int row = rh * 16 + i2;
            const int d = dstv[row];
            const float val = bf2f(h1s[row * H1STR + c]);
            if (d != cur) {
                if (cur >= 0 && mx > 0.f)
                    atomicMax((int*)agg + (size_t)cur * 128 + c, __float_as_int(mx));
                cur = d;
                mx = val;
            } else {
                mx = fmaxf(mx, val);
            }
        }
        if (cur >= 0 && mx > 0.f)
            atomicMax((int*)agg + (size_t)cur * 128 + c, __float_as_int(mx));
    }
}

// ===========================================================================
// Node MLP (MFMA, barrier-free): y = relu(relu([x,agg]@W1+b1)@W2+b2) (+x).
// ===========================================================================
template<int FIN, int KP, int FSTR, bool RES>
__global__ __launch_bounds__(256)
void node_mfma(const float* __restrict__ xin, const float* __restrict__ agg,
               const short* __restrict__ W1pk, const float* __restrict__ b1,
               const short* __restrict__ W2pk, const float* __restrict__ b2,
               float* __restrict__ out, int N)
{
    constexpr int H1STR = 136;
    __shared__ __align__(16) short sh[64 * FSTR + 64 * H1STR];
    short* feat = sh;
    short* h1s  = sh + 64 * FSTR;
    const int tid = threadIdx.x, lane = tid & 63, wave = tid >> 6;
    const int n0 = blockIdx.x * 64;

    {
        const int r = tid >> 2, s = tid & 3, n = n0 + r;
        short* frow = feat + r * FSTR;
        if (n < N) {
            const float4* xr = (const float4*)(xin + (size_t)n * FIN);
            const float4* ar = (const float4*)(agg + (size_t)n * 128);
#pragma unroll
            for (int d4 = s; d4 < FIN / 4; d4 += 4)
                *(uint2*)(frow + d4 * 4) = pk4(xr[d4]);
#pragma unroll
            for (int d4 = s; d4 < 32; d4 += 4)
                *(uint2*)(frow + FIN + d4 * 4) = pk4(ar[d4]);
        } else {
            for (int d = s * 4; d < KP; d += 16) *(short4*)(frow + d) = make_short4(0, 0, 0, 0);
        }
    }
    asm volatile("s_waitcnt lgkmcnt(0)" ::: "memory");

    f32x4 acc[8];
    mfma_gemm<KP, FSTR, 128, true>(feat, W1pk, b1, wave * 16, 0, lane, acc);
    pack_relu<H1STR>(acc, h1s, wave * 16, 0, lane);
    asm volatile("s_waitcnt lgkmcnt(0)" ::: "memory");
    mfma_gemm<128, H1STR, 128, true>(h1s, W2pk, b2, wave * 16, 0, lane, acc);
    {
        const int l15 = lane & 15, lg = lane >> 4;
#pragma unroll
        for (int f = 0; f < 8; ++f)
#pragma unroll
            for (int i = 0; i < 4; ++i) {
                const int n = n0 + wave * 16 + lg * 4 + i;
                if (n < N) {
                    const int c = f * 16 + l15;
                    float v = fmaxf(acc[f][i], 0.0f);
                    if (RES) v += xin[(size_t)n * 128 + c];
                    out[(size_t)n * 128 + c] = v;
                }
            }
    }
}

// ===========================================================================
// Fusion MLP (MFMA, barrier-free): out = relu(relu([x1,x2,x3]@W1+b1)@W2+b2).
// ===========================================================================
__global__ __launch_bounds__(128)
void fusion_mfma(const float* __restrict__ x1, const float* __restrict__ x2,
                 const float* __restrict__ x3,
                 const short* __restrict__ W1pk, const float* __restrict__ b1,
                 const short* __restrict__ W2pk, const float* __restrict__ b2,
                 float* __restrict__ out, int N)
{
    constexpr int FSTR = 392;
    constexpr int H1STR = 264;
    __shared__ __align__(16) short sh[32 * FSTR + 32 * H1STR];
    short* feat = sh;
    short* h1s  = sh + 32 * FSTR;
    const int tid = threadIdx.x, lane = tid & 63, wave = tid >> 6;
    const int n0 = blockIdx.x * 32;

    {
        const int r = tid >> 2, s = tid & 3, n = n0 + r;
        short* frow = feat + r * FSTR;
        if (n < N) {
            const float4* a1 = (const float4*)(x1 + (size_t)n * 128);
            const float4* a2 = (const float4*)(x2 + (size_t)n * 128);
            const float4* a3 = (const float4*)(x3 + (size_t)n * 128);
#pragma unroll
            for (int d4 = s; d4 < 32; d4 += 4) {
                *(uint2*)(frow + d4 * 4)       = pk4(a1[d4]);
                *(uint2*)(frow + 128 + d4 * 4) = pk4(a2[d4]);
                *(uint2*)(frow + 256 + d4 * 4) = pk4(a3[d4]);
            }
        } else {
            for (int d = s * 4; d < 384; d += 16) *(short4*)(frow + d) = make_short4(0, 0, 0, 0);
        }
    }
    asm volatile("s_waitcnt lgkmcnt(0)" ::: "memory");

    f32x4 acc[8];
#pragma unroll
    for (int c0 = 0; c0 < 256; c0 += 128) {
        mfma_gemm<384, FSTR, 256, true>(feat, W1pk, b1, wave * 16, c0, lane, acc);
        pack_relu<H1STR>(acc, h1s, wave * 16, c0, lane);
    }
    asm volatile("s_waitcnt lgkmcnt(0)" ::: "memory");
    mfma_gemm<256, H1STR, 128, true>(h1s, W2pk, b2, wave * 16, 0, lane, acc);
    {
        const int l15 = lane & 15, lg = lane >> 4;
#pragma unroll
        for (int f = 0; f < 8; ++f)
#pragma unroll
            for (int i = 0; i < 4; ++i) {
                const int n = n0 + wave * 16 + lg * 4 + i;
                if (n < N)
                    out[(size_t)n * 128 + f * 16 + l15] = fmaxf(acc[f][i], 0.0f);
            }
    }
}

// ===========================================================================
extern "C" void kernel_launch(void* const* d_in, const int* in_sizes, int n_in,
                              void* d_out, int out_size, void* d_ws, size_t ws_size,
                              hipStream_t stream)
{
    const float* x    = (const float*)d_in[0];
    const int*   eidx = (const int*)d_in[1];
    const float* ea   = (const float*)d_in[2];

    const float* c1_eW1 = (const float*)d_in[3];
    const float* c1_eb1 = (const float*)d_in[4];
    const float* c1_eW2 = (const float*)d_in[5];
    const float* c1_eb2 = (const float*)d_in[6];
    const float* c1_lW1 = (const float*)d_in[7];
    const float* c1_lb1 = (const float*)d_in[8];
    const float* c1_lW2 = (const float*)d_in[9];
    const float* c1_lb2 = (const float*)d_in[10];

    const float* c2_eW1 = (const float*)d_in[11];
    const float* c2_eb1 = (const float*)d_in[12];
    const float* c2_eW2 = (const float*)d_in[13];
    const float* c2_eb2 = (const float*)d_in[14];
    const float* c2_lW1 = (const float*)d_in[15];
    const float* c2_lb1 = (const float*)d_in[16];
    const float* c2_lW2 = (const float*)d_in[17];
    const float* c2_lb2 = (const float*)d_in[18];

    const float* c3_eW1 = (const float*)d_in[19];
    const float* c3_eb1 = (const float*)d_in[20];
    const float* c3_eW2 = (const float*)d_in[21];
    const float* c3_eb2 = (const float*)d_in[22];
    const float* c3_lW1 = (const float*)d_in[23];
    const float* c3_lb1 = (const float*)d_in[24];
    const float* c3_lW2 = (const float*)d_in[25];
    const float* c3_lb2 = (const float*)d_in[26];

    const float* fus_W1 = (const float*)d_in[27];
    const float* fus_b1 = (const float*)d_in[28];
    const float* fus_W2 = (const float*)d_in[29];
    const float* fus_b2 = (const float*)d_in[30];

    const int N = in_sizes[0] / 32;   // 25000
    const int E = in_sizes[1] / 2;    // 400000
    const int* srcI = eidx;
    const int* dstI = eidx + E;

    const size_t NP = (size_t)N * 128;
    float* ws  = (float*)d_ws;
    float* x1  = ws;
    float* x2  = x1 + NP;
    float* x3  = x2 + NP;
    float* agg = x3 + NP;
    float* sq  = agg + NP;
    int* cursor = (int*)(sq + N);
    int* sSrc   = cursor + 25024;
    int* sDst   = sSrc + E;
    short* eaB  = (short*)(sDst + E);
    short* uB   = eaB + (size_t)E * 4;
    short* vB   = uB + NP;
    short* xB   = vB + NP;
    short* wpk  = xB + NP;

    // packed-weight offsets (shorts)
    short* e1Wd = wpk + 0;        // KIN 32  KP 32   (W1a-W1b)
    short* e1Wb = wpk + 4096;     // KIN 32  KP 32   (W1b)
    short* e1Wp = wpk + 8192;     // KIN 38  KP 64   (p rows + e1,e2,ea)
    short* e1W2 = wpk + 16384;    // KIN 128 KP 128
    short* e2Wd = wpk + 32768;    // KIN 128 KP 128
    short* e2Wb = wpk + 49152;
    short* e2Wp = wpk + 65536;    // KIN 134 KP 160
    short* e2W2 = wpk + 86016;
    short* e3Wd = wpk + 102400;
    short* e3Wb = wpk + 118784;
    short* e3Wp = wpk + 135168;
    short* e3W2 = wpk + 155648;
    short* n1W1 = wpk + 172032;   // KIN 160 KP 160
    short* n1W2 = wpk + 192512;
    short* n2W1 = wpk + 208896;   // KIN 256 KP 256
    short* n2W2 = wpk + 241664;
    short* n3W1 = wpk + 258048;
    short* n3W2 = wpk + 290816;
    short* fW1  = wpk + 307200;   // KIN 384 NOUT 256
    short* fW2  = wpk + 405504;   // KIN 256
    const int packTotal = 438272;

    PackJobs pj;
    const float* pw[NPACK] = {
        c1_eW1, c1_eW1 + 32 * 128, c1_eW1 + 64 * 128, c1_eW2,
        c2_eW1, c2_eW1 + 128 * 128, c2_eW1 + 256 * 128, c2_eW2,
        c3_eW1, c3_eW1 + 128 * 128, c3_eW1 + 256 * 128, c3_eW2,
        c1_lW1, c1_lW2, c2_lW1, c2_lW2, c3_lW1, c3_lW2,
        fus_W1, fus_W2};
    const float* ps[NPACK] = {
        c1_eW1 + 32 * 128, nullptr, nullptr, nullptr,
        c2_eW1 + 128 * 128, nullptr, nullptr, nullptr,
        c3_eW1 + 128 * 128, nullptr, nullptr, nullptr,
        nullptr, nullptr, nullptr, nullptr, nullptr, nullptr,
        nullptr, nullptr};
    const int pk_kin[NPACK]  = {32, 32, 38, 128, 128, 128, 134, 128,
                                128, 128, 134, 128, 160, 128, 256, 128, 256, 128,
                                384, 256};
    const int pk_nout[NPACK] = {128, 128, 128, 128, 128, 128, 128, 128,
                                128, 128, 128, 128, 128, 128, 128, 128, 128, 128,
                                256, 128};
    const int pk_end[NPACK]  = {4096, 8192, 16384, 32768, 49152, 65536, 86016, 102400,
                                118784, 135168, 155648, 172032, 192512, 208896, 241664,
                                258048, 290816, 307200, 405504, 438272};
    for (int i = 0; i < NPACK; ++i) {
        pj.W[i] = pw[i]; pj.Wsub[i] = ps[i];
        pj.KIN[i] = pk_kin[i]; pj.NOUT[i] = pk_nout[i]; pj.end[i] = pk_end[i];
    }
    pack_all<<<(packTotal + 255) / 256, 256, 0, stream>>>(pj, wpk, packTotal);

    // ---- sort edges by dst ----
    const int eblk = (E + 255) / 256;
    hipMemsetAsync(cursor, 0, 25024 * sizeof(int), stream);
    hist_kernel<<<eblk, 256, 0, stream>>>(dstI, cursor, E);
    scan_kernel<<<1, 1024, 0, stream>>>(cursor, N);
    scatter_kernel<<<eblk, 256, 0, stream>>>(srcI, dstI, ea, cursor, sSrc, sDst, eaB, E);

    const int eblocks = (E + 63) / 64;
    const int nblocks = (N + 63) / 64;
    const int fblocks = (N + 31) / 32;
    const int swzQ = eblocks / 8, swzR = eblocks % 8;
    const size_t aggBytes = NP * sizeof(float);

    // ---- layer 1 (FIN=32) ----
    uv_pre<32, 40><<<nblocks, 256, 0, stream>>>(x, e1Wd, c1_eb1, e1Wb, uB, vB, sq, xB, N);
    hipMemsetAsync(agg, 0, aggBytes, stream);
    edge_conv7<32><<<eblocks, 512, 0, stream>>>(
        xB, sSrc, sDst, eaB, sq, uB, vB, e1Wp, e1W2, c1_eb2, agg, E, swzQ, swzR);
    node_mfma<32, 160, 168, false><<<nblocks, 256, 0, stream>>>(
        x, agg, n1W1, c1_lb1, n1W2, c1_lb2, x1, N);

    // ---- layer 2 (FIN=128, residual) ----
    uv_pre<128, 136><<<nblocks, 256, 0, stream>>>(x1, e2Wd, c2_eb1, e2Wb, uB, vB, sq, xB, N);
    hipMemsetAsync(agg, 0, aggBytes, stream);
    edge_conv7<128><<<eblocks, 512, 0, stream>>>(
        xB, sSrc, sDst, eaB, sq, uB, vB, e2Wp, e2W2, c2_eb2, agg, E, swzQ, swzR);
    node_mfma<128, 256, 264, true><<<nblocks, 256, 0, stream>>>(
        x1, agg, n2W1, c2_lb1, n2W2, c2_lb2, x2, N);

    // ---- layer 3 (FIN=128, residual) ----
    uv_pre<128, 136><<<nblocks, 256, 0, stream>>>(x2, e3Wd, c3_eb1, e3Wb, uB, vB, sq, xB, N);
    hipMemsetAsync(agg, 0, aggBytes, stream);
    edge_conv7<128><<<eblocks, 512, 0, stream>>>(
        xB, sSrc, sDst, eaB, sq, uB, vB, e3Wp, e3W2, c3_eb2, agg, E, swzQ, swzR);
    node_mfma<128, 256, 264, true><<<nblocks, 256, 0, stream>>>(
        x2, agg, n3W1, c3_lb1, n3W2, c3_lb2, x3, N);

    // ---- fusion ----
    fusion_mfma<<<fblocks, 128, 0, stream>>>(
        x1, x2, x3, fW1, fus_b1, fW2, fus_b2, (float*)d_out, N);
}